// Round 5
// baseline (483.060 us; speedup 1.0000x reference)
//
#include <hip/hip_runtime.h>
#include <hip/hip_bf16.h>

#define HEADS 12
#define HD 64
#define DIM 768
#define SEQ 1024
#define NTOK 8192      // B*N
#define TRIPLE 2304    // 3*DIM
#define BHTOT 96       // B*HEADS

typedef __attribute__((ext_vector_type(8))) short bf16x8;
typedef __attribute__((ext_vector_type(4))) float f32x4;

#define MFMA_B16(a, b, c) __builtin_amdgcn_mfma_f32_16x16x32_bf16((a), (b), (c), 0, 0, 0)

__device__ __forceinline__ unsigned short f2bf(float f) {
  unsigned int u = __float_as_uint(f);
  unsigned int r = (u + 0x7fffu + ((u >> 16) & 1u)) >> 16;
  return (unsigned short)r;
}
__device__ __forceinline__ float qclamp(float v, float lo, float hi) {
  return fminf(fmaxf(v, lo), hi);
}

// ---------------- scalar prep ----------------
__device__ float block_mean(const float* p, int n, int rnd, float* red) {
  int t = threadIdx.x;
  float s = 0.f;
  for (int i = t; i < n; i += 256) { float v = p[i]; s += rnd ? rintf(v) : v; }
  red[t] = s;
  __syncthreads();
  for (int o = 128; o > 0; o >>= 1) { if (t < o) red[t] += red[t + o]; __syncthreads(); }
  float m = red[0] / (float)n;
  __syncthreads();
  return m;
}

__global__ __launch_bounds__(256) void k_prep(
    const float* qaa, const float* qzp, const float* qa, const float* qz,
    const float* ka, const float* kz, const float* va, const float* vz,
    const float* ata, const float* atz, const float* pa, const float* pz,
    float* sc) {
  __shared__ float red[256];
  float r0 = block_mean(qaa, 768, 0, red);
  float r1 = block_mean(qzp, 768, 1, red);
  float r2 = block_mean(qa, 12, 0, red);
  float r3 = block_mean(qz, 12, 1, red);
  float r4 = block_mean(ka, 12, 0, red);
  float r5 = block_mean(kz, 12, 1, red);
  float r6 = block_mean(va, 12, 0, red);
  float r7 = block_mean(vz, 12, 1, red);
  float r8 = block_mean(ata, 12, 0, red);
  float r9 = block_mean(atz, 12, 1, red);
  float r10 = block_mean(pa, 768, 0, red);
  float r11 = block_mean(pz, 768, 1, red);
  if (threadIdx.x == 0) {
    sc[0] = r0; sc[1] = r1; sc[2] = r2; sc[3] = r3; sc[4] = r4; sc[5] = r5;
    sc[6] = r6; sc[7] = r7; sc[8] = r8; sc[9] = r9; sc[10] = r10; sc[11] = r11;
  }
}

// ---------------- activation quantize ----------------
__global__ __launch_bounds__(256) void k_quant_act(
    const float* __restrict__ x, unsigned short* __restrict__ xq,
    const float* __restrict__ sc, int n) {
  int i = (blockIdx.x * 256 + threadIdx.x) * 4;
  if (i >= n) return;
  float a = sc[0], z = sc[1];
  float4 v = *(const float4*)(x + i);
  ushort4 o;
  o.x = f2bf(rintf(qclamp(v.x / a + z, -8.f, 7.f)) - z);
  o.y = f2bf(rintf(qclamp(v.y / a + z, -8.f, 7.f)) - z);
  o.z = f2bf(rintf(qclamp(v.z / a + z, -8.f, 7.f)) - z);
  o.w = f2bf(rintf(qclamp(v.w / a + z, -8.f, 7.f)) - z);
  *(ushort4*)(xq + i) = o;
}

// ---------------- weight quantize ----------------
__global__ __launch_bounds__(256) void k_quant_w(
    const float* __restrict__ w, const float* __restrict__ alpha,
    unsigned short* __restrict__ wq, int n, int K) {
  int i = (blockIdx.x * 256 + threadIdx.x) * 4;
  if (i >= n) return;
  float a = alpha[i / K];
  float4 v = *(const float4*)(w + i);
  ushort4 o;
  o.x = f2bf(rintf(qclamp(v.x / a, -8.f, 7.f)));
  o.y = f2bf(rintf(qclamp(v.y / a, -8.f, 7.f)));
  o.z = f2bf(rintf(qclamp(v.z / a, -8.f, 7.f)));
  o.w = f2bf(rintf(qclamp(v.w / a, -8.f, 7.f)));
  *(ushort4*)(wq + i) = o;
}

// ---- global->LDS direct staging of a 128x64 u16 tile (m97 pattern) ----
// wave w, inst j covers rows w*32+j*8 .. +8; lane l -> row +(l>>3), col (l&7)*8.
// LDS linear [128][64]; per-inst wave base = w*4096 + j*1024 bytes.
__device__ __forceinline__ void stage128x64(
    const unsigned short* __restrict__ g, int ldk,
    unsigned short* lds, int wv, int l) {
#pragma unroll
  for (int j = 0; j < 4; ++j) {
    __builtin_amdgcn_global_load_lds(
        (const __attribute__((address_space(1))) void*)(
            g + (size_t)(wv * 32 + j * 8 + (l >> 3)) * ldk + (l & 7) * 8),
        (__attribute__((address_space(3))) void*)(lds + wv * 2048 + j * 512),
        16, 0, 0);
  }
}

// ---------------- qkv GEMM with fused LN+quant epilogue ----------------
// 128x128 tile, BK=64, 4 waves (64x64 quadrant each). global_load_lds staging,
// linear LDS. Each wave's 64-col range is one head's d-range -> LN via shfl.
__global__ __launch_bounds__(256) void k_gemm_qkv(
    const unsigned short* __restrict__ A, const unsigned short* __restrict__ Bw,
    const float* __restrict__ colscale, const float* __restrict__ sc,
    const float* __restrict__ nqg, const float* __restrict__ nqb,
    const float* __restrict__ nkg, const float* __restrict__ nkb,
    unsigned short* __restrict__ q2b, unsigned short* __restrict__ k2b,
    unsigned short* __restrict__ v2t) {
  __shared__ unsigned short As[128 * 64];
  __shared__ unsigned short Bs[128 * 64];
  const int t = threadIdx.x;
  const int brow = blockIdx.x * 128, bcol = blockIdx.y * 128;
  const int w = t >> 6, l = t & 63;
  const int lr = l & 15, lg = l >> 4;
  const int wr = (w >> 1) * 64, wc = (w & 1) * 64;
  f32x4 acc[4][4] = {};
  for (int kt = 0; kt < DIM; kt += 64) {
    __syncthreads();
    stage128x64(A + (size_t)brow * DIM + kt, DIM, As, w, l);
    stage128x64(Bw + (size_t)bcol * DIM + kt, DIM, Bs, w, l);
    __syncthreads();
#pragma unroll
    for (int ks = 0; ks < 2; ++ks) {
      bf16x8 af[4], bfr[4];
#pragma unroll
      for (int i = 0; i < 4; ++i) {
        af[i] = *(const bf16x8*)&As[(wr + i * 16 + lr) * 64 + ks * 32 + lg * 8];
        bfr[i] = *(const bf16x8*)&Bs[(wc + i * 16 + lr) * 64 + ks * 32 + lg * 8];
      }
#pragma unroll
      for (int i = 0; i < 4; ++i)
#pragma unroll
        for (int j = 0; j < 4; ++j)
          acc[i][j] = MFMA_B16(af[i], bfr[j], acc[i][j]);
    }
  }
  // ---- epilogue: scale, then per-segment LN/quant ----
  const float sact = sc[0];
  float s_j[4];
#pragma unroll
  for (int j = 0; j < 4; ++j) s_j[j] = sact * colscale[bcol + wc + j * 16 + lr];
#pragma unroll
  for (int i = 0; i < 4; ++i)
#pragma unroll
    for (int j = 0; j < 4; ++j)
#pragma unroll
      for (int r = 0; r < 4; ++r) acc[i][j][r] *= s_j[j];

  const int seg = bcol / DIM;                 // 0=q,1=k,2=v
  const int h_ = ((bcol % DIM) + wc) / 64;    // head for this wave
  if (seg < 2) {
    const float* gp = seg ? nkg : nqg;
    const float* bp = seg ? nkb : nqb;
    const float aq_ = seg ? sc[4] : sc[2];
    const float zq_ = seg ? sc[5] : sc[3];
    float gj[4], bj[4];
#pragma unroll
    for (int j = 0; j < 4; ++j) { gj[j] = gp[j * 16 + lr]; bj[j] = bp[j * 16 + lr]; }
    unsigned short* dstb = seg ? k2b : q2b;
#pragma unroll
    for (int i = 0; i < 4; ++i)
#pragma unroll
      for (int r = 0; r < 4; ++r) {
        float sum = acc[i][0][r] + acc[i][1][r] + acc[i][2][r] + acc[i][3][r];
        sum += __shfl_xor(sum, 1); sum += __shfl_xor(sum, 2);
        sum += __shfl_xor(sum, 4); sum += __shfl_xor(sum, 8);
        float m = sum * (1.0f / 64.0f);
        float vs = 0.f;
#pragma unroll
        for (int j = 0; j < 4; ++j) { float d = acc[i][j][r] - m; vs += d * d; }
        vs += __shfl_xor(vs, 1); vs += __shfl_xor(vs, 2);
        vs += __shfl_xor(vs, 4); vs += __shfl_xor(vs, 8);
        float inv = 1.0f / sqrtf(vs * (1.0f / 64.0f) + 1e-5f);
        int row = brow + wr + i * 16 + lg * 4 + r;
        int b_ = row >> 10, n_ = row & (SEQ - 1);
        unsigned short* dst = dstb + (((size_t)(b_ * HEADS + h_) << 10) + n_) * HD;
#pragma unroll
        for (int j = 0; j < 4; ++j) {
          float yv = (acc[i][j][r] - m) * inv * gj[j] + bj[j];
          float qv = rintf(qclamp(yv / aq_ + zq_, -8.f, 7.f)) - zq_;
          dst[j * 16 + lr] = f2bf(qv);
        }
      }
  } else {
    const float av_ = sc[6], zv = sc[7];
#pragma unroll
    for (int i = 0; i < 4; ++i)
#pragma unroll
      for (int r = 0; r < 4; ++r) {
        int row = brow + wr + i * 16 + lg * 4 + r;
        int b_ = row >> 10, n_ = row & (SEQ - 1);
        unsigned short* dst = v2t + ((size_t)(b_ * HEADS + h_) << 16) + n_;
#pragma unroll
        for (int j = 0; j < 4; ++j) {
          float qv = rintf(qclamp(acc[i][j][r] / av_ + zv, -8.f, 7.f)) - zv;
          dst[(size_t)(j * 16 + lr) * SEQ] = f2bf(qv);
        }
      }
  }
}

// ---------------- proj GEMM (f32 out + bias), global_load_lds staging ----------------
__global__ __launch_bounds__(256) void k_gemm(
    const unsigned short* __restrict__ A, const unsigned short* __restrict__ Bw,
    float* __restrict__ out, const float* __restrict__ colscale,
    const float* __restrict__ bias, const float* __restrict__ sc, int sact_idx,
    int M, int Nt, int K) {
  __shared__ unsigned short As[128 * 64];
  __shared__ unsigned short Bs[128 * 64];
  const int t = threadIdx.x;
  const int brow = blockIdx.x * 128, bcol = blockIdx.y * 128;
  const int w = t >> 6, l = t & 63;
  const int lr = l & 15, lg = l >> 4;
  const int wr = (w >> 1) * 64, wc = (w & 1) * 64;
  f32x4 acc[4][4] = {};
  for (int kt = 0; kt < K; kt += 64) {
    __syncthreads();
    stage128x64(A + (size_t)brow * K + kt, K, As, w, l);
    stage128x64(Bw + (size_t)bcol * K + kt, K, Bs, w, l);
    __syncthreads();
#pragma unroll
    for (int ks = 0; ks < 2; ++ks) {
      bf16x8 af[4], bfr[4];
#pragma unroll
      for (int i = 0; i < 4; ++i) {
        af[i] = *(const bf16x8*)&As[(wr + i * 16 + lr) * 64 + ks * 32 + lg * 8];
        bfr[i] = *(const bf16x8*)&Bs[(wc + i * 16 + lr) * 64 + ks * 32 + lg * 8];
      }
#pragma unroll
      for (int i = 0; i < 4; ++i)
#pragma unroll
        for (int j = 0; j < 4; ++j)
          acc[i][j] = MFMA_B16(af[i], bfr[j], acc[i][j]);
    }
  }
  const float sact = sc[sact_idx];
#pragma unroll
  for (int j = 0; j < 4; ++j) {
    const int col = bcol + wc + j * 16 + lr;
    const float s = sact * colscale[col];
    const float bb = bias ? bias[col] : 0.f;
#pragma unroll
    for (int i = 0; i < 4; ++i) {
      const int row0 = brow + wr + i * 16 + lg * 4;
#pragma unroll
      for (int r = 0; r < 4; ++r)
        out[(size_t)(row0 + r) * Nt + col] = acc[i][j][r] * s + bb;
    }
  }
}

// ---------------- fused attention v3: 1536 blocks for TLP ----------------
// Block = (bh, 64 q-rows); 4 waves x 16 q-rows. K/V streamed from L2.
// No max-subtraction (|S| bounded ~1.3). Per-wave Ps only; no barriers.
__global__ __launch_bounds__(256, 6) void k_attn(
    const unsigned short* __restrict__ q2b, const unsigned short* __restrict__ k2b,
    const unsigned short* __restrict__ v2t, unsigned short* __restrict__ x1q,
    const float* __restrict__ sc) {
  __shared__ unsigned short Ps[4][16][136];  // per-wave quantized P (128-k window)
  const int t = threadIdx.x;
  const int w = t >> 6, l = t & 63;
  const int lr = l & 15, lg = l >> 4;
  // XCD-bijective swizzle: 1536 = 8 * 192; all 16 q-chunks of a head on one XCD
  const int bid = (int)(blockIdx.x & 7) * 192 + (int)(blockIdx.x >> 3);
  const int bh = bid >> 4, qc = bid & 15;
  const unsigned short* Qg = q2b + (size_t)bh * (SEQ * HD);
  const unsigned short* Kg = k2b + (size_t)bh * (SEQ * HD);
  const unsigned short* Vg = v2t + (size_t)bh * (SEQ * HD);
  const float aq = sc[2], ak = sc[4], av_ = sc[6], aa = sc[8], za = sc[9];
  const float ap = sc[10], zpp = sc[11];
  const float sqk2 = aq * ak * 0.125f * 1.44269504f;  // fold log2(e)
  const float spv = aa * av_;
  const int qr0 = qc * 64 + w * 16;

  bf16x8 qf[2];
#pragma unroll
  for (int ks = 0; ks < 2; ++ks)
    qf[ks] = *(const bf16x8*)(Qg + (size_t)(qr0 + lr) * HD + ks * 32 + lg * 8);

  // ---- pass 1: denominator only
  float lacc[4] = {};
#pragma unroll 8
  for (int c = 0; c < 64; ++c) {
    const unsigned short* kr = Kg + (size_t)(c * 16 + lr) * HD + lg * 8;
    bf16x8 kf0 = *(const bf16x8*)kr;
    bf16x8 kf1 = *(const bf16x8*)(kr + 32);
    f32x4 s4 = {0.f, 0.f, 0.f, 0.f};
    s4 = MFMA_B16(qf[0], kf0, s4);
    s4 = MFMA_B16(qf[1], kf1, s4);
#pragma unroll
    for (int r = 0; r < 4; ++r)
      lacc[r] += __builtin_amdgcn_exp2f(s4[r] * sqk2);
  }
#pragma unroll
  for (int off = 1; off < 16; off <<= 1)
#pragma unroll
    for (int r = 0; r < 4; ++r) lacc[r] += __shfl_xor(lacc[r], off);
  float pinv[4];
#pragma unroll
  for (int r = 0; r < 4; ++r) pinv[r] = 1.0f / (lacc[r] * aa);

  // ---- pass 2: recompute S, quantize P -> per-wave LDS, PV (no barriers)
  f32x4 oacc[4] = {};
  for (int kt = 0; kt < SEQ; kt += 128) {
#pragma unroll
    for (int ct = 0; ct < 8; ++ct) {
      const unsigned short* kr = Kg + (size_t)(kt + ct * 16 + lr) * HD + lg * 8;
      bf16x8 kf0 = *(const bf16x8*)kr;
      bf16x8 kf1 = *(const bf16x8*)(kr + 32);
      f32x4 s4 = {0.f, 0.f, 0.f, 0.f};
      s4 = MFMA_B16(qf[0], kf0, s4);
      s4 = MFMA_B16(qf[1], kf1, s4);
#pragma unroll
      for (int r = 0; r < 4; ++r) {
        float e = __builtin_amdgcn_exp2f(s4[r] * sqk2);
        float p = fmaf(e, pinv[r], za);
        float qv = rintf(qclamp(p, 0.f, 15.f)) - za;
        Ps[w][lg * 4 + r][ct * 16 + lr] = f2bf(qv);
      }
    }
#pragma unroll
    for (int ks2 = 0; ks2 < 4; ++ks2) {
      bf16x8 vf[4], pf;
#pragma unroll
      for (int dt = 0; dt < 4; ++dt)
        vf[dt] = *(const bf16x8*)(Vg + (size_t)(dt * 16 + lr) * SEQ + kt + ks2 * 32 + lg * 8);
      pf = *(const bf16x8*)&Ps[w][lr][ks2 * 32 + lg * 8];
#pragma unroll
      for (int dt = 0; dt < 4; ++dt)
        oacc[dt] = MFMA_B16(pf, vf[dt], oacc[dt]);
    }
  }
  // ---- epilogue: x1 = spv*acc, fused proj-input quantization
  const int b_ = bh / HEADS, h_ = bh % HEADS;
#pragma unroll
  for (int dt = 0; dt < 4; ++dt) {
    const int col = h_ * HD + dt * 16 + lr;
#pragma unroll
    for (int r = 0; r < 4; ++r) {
      const int qrow = qr0 + lg * 4 + r;
      float x1v = oacc[dt][r] * spv;
      float xv = rintf(qclamp(x1v / ap + zpp, -8.f, 7.f)) - zpp;
      x1q[(size_t)(b_ * SEQ + qrow) * DIM + col] = f2bf(xv);
    }
  }
}

extern "C" void kernel_launch(void* const* d_in, const int* in_sizes, int n_in,
                              void* d_out, int out_size, void* d_ws, size_t ws_size,
                              hipStream_t stream) {
  const float* x0      = (const float*)d_in[0];
  const float* qkvw    = (const float*)d_in[1];
  const float* qkv_aw  = (const float*)d_in[2];
  const float* qkv_aa  = (const float*)d_in[3];
  const float* qkv_azp = (const float*)d_in[4];
  const float* nqg     = (const float*)d_in[5];
  const float* nqb     = (const float*)d_in[6];
  const float* nkg     = (const float*)d_in[7];
  const float* nkb     = (const float*)d_in[8];
  const float* q_a     = (const float*)d_in[9];
  const float* q_z     = (const float*)d_in[10];
  const float* k_a     = (const float*)d_in[11];
  const float* k_z     = (const float*)d_in[12];
  const float* v_a     = (const float*)d_in[13];
  const float* v_z     = (const float*)d_in[14];
  const float* at_a    = (const float*)d_in[15];
  const float* at_z    = (const float*)d_in[16];
  const float* pw      = (const float*)d_in[17];
  const float* pb      = (const float*)d_in[18];
  const float* p_aw    = (const float*)d_in[19];
  const float* p_aa    = (const float*)d_in[20];
  const float* p_azp   = (const float*)d_in[21];
  float* out = (float*)d_out;

  char* ws = (char*)d_ws;
  size_t off = 0;
  float* scal = (float*)(ws); off = 256;
  unsigned short* x0q  = (unsigned short*)(ws + off); off += (size_t)NTOK * DIM * 2;
  unsigned short* qwq  = (unsigned short*)(ws + off); off += (size_t)TRIPLE * DIM * 2;
  unsigned short* pwq  = (unsigned short*)(ws + off); off += (size_t)DIM * DIM * 2;
  unsigned short* q2b  = (unsigned short*)(ws + off); off += (size_t)BHTOT * SEQ * HD * 2;
  unsigned short* k2b  = (unsigned short*)(ws + off); off += (size_t)BHTOT * SEQ * HD * 2;
  unsigned short* v2t  = (unsigned short*)(ws + off); off += (size_t)BHTOT * SEQ * HD * 2;
  unsigned short* x1q  = (unsigned short*)(ws + off); off += (size_t)NTOK * DIM * 2;

  k_prep<<<1, 256, 0, stream>>>(qkv_aa, qkv_azp, q_a, q_z, k_a, k_z, v_a, v_z,
                                at_a, at_z, p_aa, p_azp, scal);
  k_quant_act<<<(NTOK * DIM) / 1024, 256, 0, stream>>>(x0, x0q, scal, NTOK * DIM);
  k_quant_w<<<(TRIPLE * DIM) / 1024, 256, 0, stream>>>(qkvw, qkv_aw, qwq, TRIPLE * DIM, DIM);
  k_quant_w<<<(DIM * DIM) / 1024, 256, 0, stream>>>(pw, p_aw, pwq, DIM * DIM, DIM);
  k_gemm_qkv<<<dim3(NTOK / 128, TRIPLE / 128), 256, 0, stream>>>(
      x0q, qwq, qkv_aw, scal, nqg, nqb, nkg, nkb, q2b, k2b, v2t);
  k_attn<<<BHTOT * 16, 256, 0, stream>>>(q2b, k2b, v2t, x1q, scal);
  k_gemm<<<dim3(NTOK / 128, DIM / 128), 256, 0, stream>>>(
      x1q, pwq, out, p_aw, pb, scal, 10, NTOK, DIM, DIM);
}

// Round 7
// 291.095 us; speedup vs baseline: 1.6595x; 1.6595x over previous
//
#include <hip/hip_runtime.h>
#include <hip/hip_bf16.h>

#define HEADS 12
#define HD 64
#define DIM 768
#define SEQ 1024
#define NTOK 8192      // B*N
#define TRIPLE 2304    // 3*DIM
#define BHTOT 96       // B*HEADS

typedef __attribute__((ext_vector_type(8))) short bf16x8;
typedef __attribute__((ext_vector_type(4))) float f32x4;

#define MFMA_B16(a, b, c) __builtin_amdgcn_mfma_f32_16x16x32_bf16((a), (b), (c), 0, 0, 0)

__device__ __forceinline__ unsigned short f2bf(float f) {
  unsigned int u = __float_as_uint(f);
  unsigned int r = (u + 0x7fffu + ((u >> 16) & 1u)) >> 16;
  return (unsigned short)r;
}
__device__ __forceinline__ float qclamp(float v, float lo, float hi) {
  return fminf(fmaxf(v, lo), hi);
}

// ---------------- scalar prep ----------------
__device__ float block_mean(const float* p, int n, int rnd, float* red) {
  int t = threadIdx.x;
  float s = 0.f;
  for (int i = t; i < n; i += 256) { float v = p[i]; s += rnd ? rintf(v) : v; }
  red[t] = s;
  __syncthreads();
  for (int o = 128; o > 0; o >>= 1) { if (t < o) red[t] += red[t + o]; __syncthreads(); }
  float m = red[0] / (float)n;
  __syncthreads();
  return m;
}

__global__ __launch_bounds__(256) void k_prep(
    const float* qaa, const float* qzp, const float* qa, const float* qz,
    const float* ka, const float* kz, const float* va, const float* vz,
    const float* ata, const float* atz, const float* pa, const float* pz,
    float* sc) {
  __shared__ float red[256];
  float r0 = block_mean(qaa, 768, 0, red);
  float r1 = block_mean(qzp, 768, 1, red);
  float r2 = block_mean(qa, 12, 0, red);
  float r3 = block_mean(qz, 12, 1, red);
  float r4 = block_mean(ka, 12, 0, red);
  float r5 = block_mean(kz, 12, 1, red);
  float r6 = block_mean(va, 12, 0, red);
  float r7 = block_mean(vz, 12, 1, red);
  float r8 = block_mean(ata, 12, 0, red);
  float r9 = block_mean(atz, 12, 1, red);
  float r10 = block_mean(pa, 768, 0, red);
  float r11 = block_mean(pz, 768, 1, red);
  if (threadIdx.x == 0) {
    sc[0] = r0; sc[1] = r1; sc[2] = r2; sc[3] = r3; sc[4] = r4; sc[5] = r5;
    sc[6] = r6; sc[7] = r7; sc[8] = r8; sc[9] = r9; sc[10] = r10; sc[11] = r11;
  }
}

// ---------------- activation quantize ----------------
__global__ __launch_bounds__(256) void k_quant_act(
    const float* __restrict__ x, unsigned short* __restrict__ xq,
    const float* __restrict__ sc, int n) {
  int i = (blockIdx.x * 256 + threadIdx.x) * 4;
  if (i >= n) return;
  float a = sc[0], z = sc[1];
  float4 v = *(const float4*)(x + i);
  ushort4 o;
  o.x = f2bf(rintf(qclamp(v.x / a + z, -8.f, 7.f)) - z);
  o.y = f2bf(rintf(qclamp(v.y / a + z, -8.f, 7.f)) - z);
  o.z = f2bf(rintf(qclamp(v.z / a + z, -8.f, 7.f)) - z);
  o.w = f2bf(rintf(qclamp(v.w / a + z, -8.f, 7.f)) - z);
  *(ushort4*)(xq + i) = o;
}

// ---------------- weight quantize ----------------
__global__ __launch_bounds__(256) void k_quant_w(
    const float* __restrict__ w, const float* __restrict__ alpha,
    unsigned short* __restrict__ wq, int n, int K) {
  int i = (blockIdx.x * 256 + threadIdx.x) * 4;
  if (i >= n) return;
  float a = alpha[i / K];
  float4 v = *(const float4*)(w + i);
  ushort4 o;
  o.x = f2bf(rintf(qclamp(v.x / a, -8.f, 7.f)));
  o.y = f2bf(rintf(qclamp(v.y / a, -8.f, 7.f)));
  o.z = f2bf(rintf(qclamp(v.z / a, -8.f, 7.f)));
  o.w = f2bf(rintf(qclamp(v.w / a, -8.f, 7.f)));
  *(ushort4*)(wq + i) = o;
}

// ---- global->LDS direct staging of a 128x64 u16 tile (m97 pattern) ----
__device__ __forceinline__ void stage128x64(
    const unsigned short* __restrict__ g, int ldk,
    unsigned short* lds, int wv, int l) {
#pragma unroll
  for (int j = 0; j < 4; ++j) {
    __builtin_amdgcn_global_load_lds(
        (const __attribute__((address_space(1))) void*)(
            g + (size_t)(wv * 32 + j * 8 + (l >> 3)) * ldk + (l & 7) * 8),
        (__attribute__((address_space(3))) void*)(lds + wv * 2048 + j * 512),
        16, 0, 0);
  }
}

// ---------------- qkv GEMM with fused LN+quant epilogue ----------------
__global__ __launch_bounds__(256) void k_gemm_qkv(
    const unsigned short* __restrict__ A, const unsigned short* __restrict__ Bw,
    const float* __restrict__ colscale, const float* __restrict__ sc,
    const float* __restrict__ nqg, const float* __restrict__ nqb,
    const float* __restrict__ nkg, const float* __restrict__ nkb,
    unsigned short* __restrict__ q2b, unsigned short* __restrict__ k2b,
    unsigned short* __restrict__ v2t) {
  __shared__ unsigned short As[128 * 64];
  __shared__ unsigned short Bs[128 * 64];
  const int t = threadIdx.x;
  const int brow = blockIdx.x * 128, bcol = blockIdx.y * 128;
  const int w = t >> 6, l = t & 63;
  const int lr = l & 15, lg = l >> 4;
  const int wr = (w >> 1) * 64, wc = (w & 1) * 64;
  f32x4 acc[4][4] = {};
  for (int kt = 0; kt < DIM; kt += 64) {
    __syncthreads();
    stage128x64(A + (size_t)brow * DIM + kt, DIM, As, w, l);
    stage128x64(Bw + (size_t)bcol * DIM + kt, DIM, Bs, w, l);
    __syncthreads();
#pragma unroll
    for (int ks = 0; ks < 2; ++ks) {
      bf16x8 af[4], bfr[4];
#pragma unroll
      for (int i = 0; i < 4; ++i) {
        af[i] = *(const bf16x8*)&As[(wr + i * 16 + lr) * 64 + ks * 32 + lg * 8];
        bfr[i] = *(const bf16x8*)&Bs[(wc + i * 16 + lr) * 64 + ks * 32 + lg * 8];
      }
#pragma unroll
      for (int i = 0; i < 4; ++i)
#pragma unroll
        for (int j = 0; j < 4; ++j)
          acc[i][j] = MFMA_B16(af[i], bfr[j], acc[i][j]);
    }
  }
  // ---- epilogue: scale, then per-segment LN/quant ----
  const float sact = sc[0];
  float s_j[4];
#pragma unroll
  for (int j = 0; j < 4; ++j) s_j[j] = sact * colscale[bcol + wc + j * 16 + lr];
#pragma unroll
  for (int i = 0; i < 4; ++i)
#pragma unroll
    for (int j = 0; j < 4; ++j)
#pragma unroll
      for (int r = 0; r < 4; ++r) acc[i][j][r] *= s_j[j];

  const int seg = bcol / DIM;                 // 0=q,1=k,2=v
  const int h_ = ((bcol % DIM) + wc) / 64;    // head for this wave
  if (seg < 2) {
    const float* gp = seg ? nkg : nqg;
    const float* bp = seg ? nkb : nqb;
    const float aq_ = seg ? sc[4] : sc[2];
    const float zq_ = seg ? sc[5] : sc[3];
    float gj[4], bj[4];
#pragma unroll
    for (int j = 0; j < 4; ++j) { gj[j] = gp[j * 16 + lr]; bj[j] = bp[j * 16 + lr]; }
    unsigned short* dstb = seg ? k2b : q2b;
#pragma unroll
    for (int i = 0; i < 4; ++i)
#pragma unroll
      for (int r = 0; r < 4; ++r) {
        float sum = acc[i][0][r] + acc[i][1][r] + acc[i][2][r] + acc[i][3][r];
        sum += __shfl_xor(sum, 1); sum += __shfl_xor(sum, 2);
        sum += __shfl_xor(sum, 4); sum += __shfl_xor(sum, 8);
        float m = sum * (1.0f / 64.0f);
        float vs = 0.f;
#pragma unroll
        for (int j = 0; j < 4; ++j) { float d = acc[i][j][r] - m; vs += d * d; }
        vs += __shfl_xor(vs, 1); vs += __shfl_xor(vs, 2);
        vs += __shfl_xor(vs, 4); vs += __shfl_xor(vs, 8);
        float inv = 1.0f / sqrtf(vs * (1.0f / 64.0f) + 1e-5f);
        int row = brow + wr + i * 16 + lg * 4 + r;
        int b_ = row >> 10, n_ = row & (SEQ - 1);
        unsigned short* dst = dstb + (((size_t)(b_ * HEADS + h_) << 10) + n_) * HD;
#pragma unroll
        for (int j = 0; j < 4; ++j) {
          float yv = (acc[i][j][r] - m) * inv * gj[j] + bj[j];
          float qv = rintf(qclamp(yv / aq_ + zq_, -8.f, 7.f)) - zq_;
          dst[j * 16 + lr] = f2bf(qv);
        }
      }
  } else {
    const float av_ = sc[6], zv = sc[7];
#pragma unroll
    for (int i = 0; i < 4; ++i)
#pragma unroll
      for (int r = 0; r < 4; ++r) {
        int row = brow + wr + i * 16 + lg * 4 + r;
        int b_ = row >> 10, n_ = row & (SEQ - 1);
        unsigned short* dst = v2t + ((size_t)(b_ * HEADS + h_) << 16) + n_;
#pragma unroll
        for (int j = 0; j < 4; ++j) {
          float qv = rintf(qclamp(acc[i][j][r] / av_ + zv, -8.f, 7.f)) - zv;
          dst[(size_t)(j * 16 + lr) * SEQ] = f2bf(qv);
        }
      }
  }
}

// ---------------- proj GEMM (f32 out + bias) ----------------
__global__ __launch_bounds__(256) void k_gemm(
    const unsigned short* __restrict__ A, const unsigned short* __restrict__ Bw,
    float* __restrict__ out, const float* __restrict__ colscale,
    const float* __restrict__ bias, const float* __restrict__ sc, int sact_idx,
    int M, int Nt, int K) {
  __shared__ unsigned short As[128 * 64];
  __shared__ unsigned short Bs[128 * 64];
  const int t = threadIdx.x;
  const int brow = blockIdx.x * 128, bcol = blockIdx.y * 128;
  const int w = t >> 6, l = t & 63;
  const int lr = l & 15, lg = l >> 4;
  const int wr = (w >> 1) * 64, wc = (w & 1) * 64;
  f32x4 acc[4][4] = {};
  for (int kt = 0; kt < K; kt += 64) {
    __syncthreads();
    stage128x64(A + (size_t)brow * K + kt, K, As, w, l);
    stage128x64(Bw + (size_t)bcol * K + kt, K, Bs, w, l);
    __syncthreads();
#pragma unroll
    for (int ks = 0; ks < 2; ++ks) {
      bf16x8 af[4], bfr[4];
#pragma unroll
      for (int i = 0; i < 4; ++i) {
        af[i] = *(const bf16x8*)&As[(wr + i * 16 + lr) * 64 + ks * 32 + lg * 8];
        bfr[i] = *(const bf16x8*)&Bs[(wc + i * 16 + lr) * 64 + ks * 32 + lg * 8];
      }
#pragma unroll
      for (int i = 0; i < 4; ++i)
#pragma unroll
        for (int j = 0; j < 4; ++j)
          acc[i][j] = MFMA_B16(af[i], bfr[j], acc[i][j]);
    }
  }
  const float sact = sc[sact_idx];
#pragma unroll
  for (int j = 0; j < 4; ++j) {
    const int col = bcol + wc + j * 16 + lr;
    const float s = sact * colscale[col];
    const float bb = bias ? bias[col] : 0.f;
#pragma unroll
    for (int i = 0; i < 4; ++i) {
      const int row0 = brow + wr + i * 16 + lg * 4;
#pragma unroll
      for (int r = 0; r < 4; ++r)
        out[(size_t)(row0 + r) * Nt + col] = acc[i][j][r] * s + bb;
    }
  }
}

// ---------------- fused attention v4: cooperative staging + no-max softmax ----
// Block = (bh, 128 q-rows), 4 waves x 32 q-rows. K/V reg-staged into padded
// LDS once per block per tile (kills per-wave L1/L2 amplification). P
// quantized in 32-col chunks interleaved with PV (small Ps -> 45KB LDS,
// 3 blocks/CU). No max-subtraction (|S| <= ~1.3 by quantization bounds).
__global__ __launch_bounds__(256, 3) void k_attn(
    const unsigned short* __restrict__ q2b, const unsigned short* __restrict__ k2b,
    const unsigned short* __restrict__ v2t, unsigned short* __restrict__ x1q,
    const float* __restrict__ sc) {
  __shared__ unsigned short Ks[128][72];    // k rows x d (padded, 144B rows)
  __shared__ unsigned short Vs[64][136];    // d x k-tile (padded, 272B rows)
  __shared__ unsigned short Ps[4][32][40];  // per-wave quantized P, 32-col chunk
  const int t = threadIdx.x;
  const int w = t >> 6, l = t & 63;
  const int lr = l & 15, lg = l >> 4;
  // XCD-bijective swizzle: 768 = 8 * 96
  const int bid = (int)(blockIdx.x & 7) * 96 + (int)(blockIdx.x >> 3);
  const int bh = bid >> 3, qc = bid & 7;
  const unsigned short* Qg = q2b + (size_t)bh * (SEQ * HD);
  const unsigned short* Kg = k2b + (size_t)bh * (SEQ * HD);
  const unsigned short* Vg = v2t + (size_t)bh * (SEQ * HD);
  const float aq = sc[2], ak = sc[4], av_ = sc[6], aa = sc[8], za = sc[9];
  const float ap = sc[10], zpp = sc[11];
  const float sqk2 = aq * ak * 0.125f * 1.44269504f;  // fold log2(e)
  const float spv = aa * av_;
  const int qr0 = qc * 128 + w * 32;

  bf16x8 qf[2][2];
#pragma unroll
  for (int rt = 0; rt < 2; ++rt)
#pragma unroll
    for (int ks = 0; ks < 2; ++ks)
      qf[rt][ks] = *(const bf16x8*)(Qg + (size_t)(qr0 + rt * 16 + lr) * HD + ks * 32 + lg * 8);

  const int sr = t >> 1, sc0 = (t & 1) * 32;
  const int vr = t >> 2, vc0 = (t & 3) * 32;

  // ---- pass 1: denominator only
  float lacc[2][4] = {};
  for (int kt = 0; kt < SEQ; kt += 128) {
    const uint4* g = (const uint4*)(Kg + (size_t)(kt + sr) * HD + sc0);
    uint4 u0 = g[0], u1 = g[1], u2 = g[2], u3 = g[3];
    __syncthreads();
    { uint4* d = (uint4*)&Ks[sr][sc0]; d[0] = u0; d[1] = u1; d[2] = u2; d[3] = u3; }
    __syncthreads();
#pragma unroll
    for (int ct = 0; ct < 8; ++ct) {
      const int kl = ct * 16 + lr;
      bf16x8 kf0 = *(const bf16x8*)&Ks[kl][lg * 8];
      bf16x8 kf1 = *(const bf16x8*)&Ks[kl][32 + lg * 8];
#pragma unroll
      for (int rt = 0; rt < 2; ++rt) {
        f32x4 s4 = {0.f, 0.f, 0.f, 0.f};
        s4 = MFMA_B16(qf[rt][0], kf0, s4);
        s4 = MFMA_B16(qf[rt][1], kf1, s4);
#pragma unroll
        for (int r = 0; r < 4; ++r)
          lacc[rt][r] += __builtin_amdgcn_exp2f(s4[r] * sqk2);
      }
    }
  }
#pragma unroll
  for (int off = 1; off < 16; off <<= 1)
#pragma unroll
    for (int rt = 0; rt < 2; ++rt)
#pragma unroll
      for (int r = 0; r < 4; ++r) lacc[rt][r] += __shfl_xor(lacc[rt][r], off);
  float pinv[2][4];
#pragma unroll
  for (int rt = 0; rt < 2; ++rt)
#pragma unroll
    for (int r = 0; r < 4; ++r) pinv[rt][r] = 1.0f / (lacc[rt][r] * aa);

  // ---- pass 2: recompute S, quantize P (32-col chunks) interleaved with PV
  f32x4 oacc[2][4] = {};
  for (int kt = 0; kt < SEQ; kt += 128) {
    const uint4* gk = (const uint4*)(Kg + (size_t)(kt + sr) * HD + sc0);
    uint4 u0 = gk[0], u1 = gk[1], u2 = gk[2], u3 = gk[3];
    const uint4* gv = (const uint4*)(Vg + (size_t)vr * SEQ + kt + vc0);
    uint4 w0 = gv[0], w1 = gv[1], w2 = gv[2], w3 = gv[3];
    __syncthreads();
    { uint4* d = (uint4*)&Ks[sr][sc0]; d[0] = u0; d[1] = u1; d[2] = u2; d[3] = u3; }
    { uint4* d = (uint4*)&Vs[vr][vc0]; d[0] = w0; d[1] = w1; d[2] = w2; d[3] = w3; }
    __syncthreads();
#pragma unroll
    for (int q4 = 0; q4 < 4; ++q4) {
      // quantize 2 x 16 k-cols of P into this wave's Ps chunk
#pragma unroll
      for (int c2 = 0; c2 < 2; ++c2) {
        const int ct = q4 * 2 + c2;
        const int kl = ct * 16 + lr;
        bf16x8 kf0 = *(const bf16x8*)&Ks[kl][lg * 8];
        bf16x8 kf1 = *(const bf16x8*)&Ks[kl][32 + lg * 8];
#pragma unroll
        for (int rt = 0; rt < 2; ++rt) {
          f32x4 s4 = {0.f, 0.f, 0.f, 0.f};
          s4 = MFMA_B16(qf[rt][0], kf0, s4);
          s4 = MFMA_B16(qf[rt][1], kf1, s4);
#pragma unroll
          for (int r = 0; r < 4; ++r) {
            float e = __builtin_amdgcn_exp2f(s4[r] * sqk2);
            float p = fmaf(e, pinv[rt][r], za);
            float qv = rintf(qclamp(p, 0.f, 15.f)) - za;
            Ps[w][rt * 16 + lg * 4 + r][c2 * 16 + lr] = f2bf(qv);
          }
        }
      }
      // PV on this 32-k-slot chunk
      bf16x8 vf[4], pf[2];
#pragma unroll
      for (int dt = 0; dt < 4; ++dt)
        vf[dt] = *(const bf16x8*)&Vs[dt * 16 + lr][q4 * 32 + lg * 8];
#pragma unroll
      for (int rt = 0; rt < 2; ++rt)
        pf[rt] = *(const bf16x8*)&Ps[w][rt * 16 + lr][lg * 8];
#pragma unroll
      for (int rt = 0; rt < 2; ++rt)
#pragma unroll
        for (int dt = 0; dt < 4; ++dt)
          oacc[rt][dt] = MFMA_B16(pf[rt], vf[dt], oacc[rt][dt]);
    }
  }
  // ---- epilogue: x1 = spv*acc, fused proj-input quantization
  const int b_ = bh / HEADS, h_ = bh % HEADS;
#pragma unroll
  for (int rt = 0; rt < 2; ++rt)
#pragma unroll
    for (int dt = 0; dt < 4; ++dt) {
      const int col = h_ * HD + dt * 16 + lr;
#pragma unroll
      for (int r = 0; r < 4; ++r) {
        const int qrow = qr0 + rt * 16 + lg * 4 + r;
        float x1v = oacc[rt][dt][r] * spv;
        float xv = rintf(qclamp(x1v / ap + zpp, -8.f, 7.f)) - zpp;
        x1q[(size_t)(b_ * SEQ + qrow) * DIM + col] = f2bf(xv);
      }
    }
}

extern "C" void kernel_launch(void* const* d_in, const int* in_sizes, int n_in,
                              void* d_out, int out_size, void* d_ws, size_t ws_size,
                              hipStream_t stream) {
  const float* x0      = (const float*)d_in[0];
  const float* qkvw    = (const float*)d_in[1];
  const float* qkv_aw  = (const float*)d_in[2];
  const float* qkv_aa  = (const float*)d_in[3];
  const float* qkv_azp = (const float*)d_in[4];
  const float* nqg     = (const float*)d_in[5];
  const float* nqb     = (const float*)d_in[6];
  const float* nkg     = (const float*)d_in[7];
  const float* nkb     = (const float*)d_in[8];
  const float* q_a     = (const float*)d_in[9];
  const float* q_z     = (const float*)d_in[10];
  const float* k_a     = (const float*)d_in[11];
  const float* k_z     = (const float*)d_in[12];
  const float* v_a     = (const float*)d_in[13];
  const float* v_z     = (const float*)d_in[14];
  const float* at_a    = (const float*)d_in[15];
  const float* at_z    = (const float*)d_in[16];
  const float* pw      = (const float*)d_in[17];
  const float* pb      = (const float*)d_in[18];
  const float* p_aw    = (const float*)d_in[19];
  const float* p_aa    = (const float*)d_in[20];
  const float* p_azp   = (const float*)d_in[21];
  float* out = (float*)d_out;

  char* ws = (char*)d_ws;
  size_t off = 0;
  float* scal = (float*)(ws); off = 256;
  unsigned short* x0q  = (unsigned short*)(ws + off); off += (size_t)NTOK * DIM * 2;
  unsigned short* qwq  = (unsigned short*)(ws + off); off += (size_t)TRIPLE * DIM * 2;
  unsigned short* pwq  = (unsigned short*)(ws + off); off += (size_t)DIM * DIM * 2;
  unsigned short* q2b  = (unsigned short*)(ws + off); off += (size_t)BHTOT * SEQ * HD * 2;
  unsigned short* k2b  = (unsigned short*)(ws + off); off += (size_t)BHTOT * SEQ * HD * 2;
  unsigned short* v2t  = (unsigned short*)(ws + off); off += (size_t)BHTOT * SEQ * HD * 2;
  unsigned short* x1q  = (unsigned short*)(ws + off); off += (size_t)NTOK * DIM * 2;

  k_prep<<<1, 256, 0, stream>>>(qkv_aa, qkv_azp, q_a, q_z, k_a, k_z, v_a, v_z,
                                at_a, at_z, p_aa, p_azp, scal);
  k_quant_act<<<(NTOK * DIM) / 1024, 256, 0, stream>>>(x0, x0q, scal, NTOK * DIM);
  k_quant_w<<<(TRIPLE * DIM) / 1024, 256, 0, stream>>>(qkvw, qkv_aw, qwq, TRIPLE * DIM, DIM);
  k_quant_w<<<(DIM * DIM) / 1024, 256, 0, stream>>>(pw, p_aw, pwq, DIM * DIM, DIM);
  k_gemm_qkv<<<dim3(NTOK / 128, TRIPLE / 128), 256, 0, stream>>>(
      x0q, qwq, qkv_aw, scal, nqg, nqb, nkg, nkb, q2b, k2b, v2t);
  k_attn<<<BHTOT * 8, 256, 0, stream>>>(q2b, k2b, v2t, x1q, scal);
  k_gemm<<<dim3(NTOK / 128, DIM / 128), 256, 0, stream>>>(
      x1q, pwq, out, p_aw, pb, scal, 10, NTOK, DIM, DIM);
}

// Round 9
// 270.454 us; speedup vs baseline: 1.7861x; 1.0763x over previous
//
#include <hip/hip_runtime.h>
#include <hip/hip_bf16.h>

#define HEADS 12
#define HD 64
#define DIM 768
#define SEQ 1024
#define NTOK 8192      // B*N
#define TRIPLE 2304    // 3*DIM
#define BHTOT 96       // B*HEADS

typedef __attribute__((ext_vector_type(8))) short bf16x8;
typedef __attribute__((ext_vector_type(4))) float f32x4;
typedef __attribute__((ext_vector_type(4))) int i32x4;

#define MFMA_B16(a, b, c) __builtin_amdgcn_mfma_f32_16x16x32_bf16((a), (b), (c), 0, 0, 0)
#define MFMA_I8(a, b, c) __builtin_amdgcn_mfma_i32_16x16x64_i8((a), (b), (c), 0, 0, 0)

__device__ __forceinline__ unsigned short f2bf(float f) {
  unsigned int u = __float_as_uint(f);
  unsigned int r = (u + 0x7fffu + ((u >> 16) & 1u)) >> 16;
  return (unsigned short)r;
}
__device__ __forceinline__ float qclamp(float v, float lo, float hi) {
  return fminf(fmaxf(v, lo), hi);
}

// ---------------- scalar prep ----------------
__device__ float block_mean(const float* p, int n, int rnd, float* red) {
  int t = threadIdx.x;
  float s = 0.f;
  for (int i = t; i < n; i += 256) { float v = p[i]; s += rnd ? rintf(v) : v; }
  red[t] = s;
  __syncthreads();
  for (int o = 128; o > 0; o >>= 1) { if (t < o) red[t] += red[t + o]; __syncthreads(); }
  float m = red[0] / (float)n;
  __syncthreads();
  return m;
}

__global__ __launch_bounds__(256) void k_prep(
    const float* qaa, const float* qzp, const float* qa, const float* qz,
    const float* ka, const float* kz, const float* va, const float* vz,
    const float* ata, const float* atz, const float* pa, const float* pz,
    float* sc) {
  __shared__ float red[256];
  float r0 = block_mean(qaa, 768, 0, red);
  float r1 = block_mean(qzp, 768, 1, red);
  float r2 = block_mean(qa, 12, 0, red);
  float r3 = block_mean(qz, 12, 1, red);
  float r4 = block_mean(ka, 12, 0, red);
  float r5 = block_mean(kz, 12, 1, red);
  float r6 = block_mean(va, 12, 0, red);
  float r7 = block_mean(vz, 12, 1, red);
  float r8 = block_mean(ata, 12, 0, red);
  float r9 = block_mean(atz, 12, 1, red);
  float r10 = block_mean(pa, 768, 0, red);
  float r11 = block_mean(pz, 768, 1, red);
  if (threadIdx.x == 0) {
    sc[0] = r0; sc[1] = r1; sc[2] = r2; sc[3] = r3; sc[4] = r4; sc[5] = r5;
    sc[6] = r6; sc[7] = r7; sc[8] = r8; sc[9] = r9; sc[10] = r10; sc[11] = r11;
  }
}

// ---------------- activation quantize: store INT part as i8 (z handled via wsum) ----------------
__global__ __launch_bounds__(256) void k_quant_act(
    const float* __restrict__ x, signed char* __restrict__ xq,
    const float* __restrict__ sc, int n) {
  int i = (blockIdx.x * 256 + threadIdx.x) * 4;
  if (i >= n) return;
  float a = sc[0], z = sc[1];
  float4 v = *(const float4*)(x + i);
  int b0 = (int)rintf(qclamp(v.x / a + z, -8.f, 7.f));
  int b1 = (int)rintf(qclamp(v.y / a + z, -8.f, 7.f));
  int b2 = (int)rintf(qclamp(v.z / a + z, -8.f, 7.f));
  int b3 = (int)rintf(qclamp(v.w / a + z, -8.f, 7.f));
  ((int*)xq)[i >> 2] = (b0 & 255) | ((b1 & 255) << 8) | ((b2 & 255) << 16) | (b3 << 24);
}

// ---------------- weight quantize -> i8 ----------------
__global__ __launch_bounds__(256) void k_quant_w(
    const float* __restrict__ w, const float* __restrict__ alpha,
    signed char* __restrict__ wq, int n, int K) {
  int i = (blockIdx.x * 256 + threadIdx.x) * 4;
  if (i >= n) return;
  float a = alpha[i / K];
  float4 v = *(const float4*)(w + i);
  int b0 = (int)rintf(qclamp(v.x / a, -8.f, 7.f));
  int b1 = (int)rintf(qclamp(v.y / a, -8.f, 7.f));
  int b2 = (int)rintf(qclamp(v.z / a, -8.f, 7.f));
  int b3 = (int)rintf(qclamp(v.w / a, -8.f, 7.f));
  ((int*)wq)[i >> 2] = (b0 & 255) | ((b1 & 255) << 8) | ((b2 & 255) << 16) | (b3 << 24);
}

// ---------------- per-out-row weight int sums (zero-point correction) ----------------
__global__ __launch_bounds__(256) void k_wsum(
    const signed char* __restrict__ wq, float* __restrict__ s, int K) {
  const int w = threadIdx.x >> 6, l = threadIdx.x & 63;
  const int row = blockIdx.x * 4 + w;
  const int* rp = (const int*)(wq + (size_t)row * K);
  int acc = 0;
  for (int idx = l; idx < K / 4; idx += 64) {
    int u = rp[idx];
    acc += (int)(signed char)u + (int)(signed char)(u >> 8) +
           (int)(signed char)(u >> 16) + (int)(signed char)(u >> 24);
  }
#pragma unroll
  for (int off = 32; off > 0; off >>= 1) acc += __shfl_xor(acc, off);
  if (l == 0) s[row] = (float)acc;
}

// ---- global->LDS direct staging of a 128x128 i8 tile ----
// wave w, inst j covers rows w*32+j*8..+8; lane l -> row +(l>>3), byte col (l&7)*16.
__device__ __forceinline__ void stage_i8(
    const signed char* __restrict__ g, int ldk,
    signed char* lds, int wv, int l) {
#pragma unroll
  for (int j = 0; j < 4; ++j) {
    __builtin_amdgcn_global_load_lds(
        (const __attribute__((address_space(1))) void*)(
            g + (size_t)(wv * 32 + j * 8 + (l >> 3)) * ldk + (l & 7) * 16),
        (__attribute__((address_space(3))) void*)(lds + wv * 4096 + j * 1024),
        16, 0, 0);
  }
}

// ---------------- qkv GEMM (i8, BK=128) with fused LN+quant epilogue ----------------
__global__ __launch_bounds__(256) void k_gemm_qkv(
    const signed char* __restrict__ A, const signed char* __restrict__ Bw,
    const float* __restrict__ colscale, const float* __restrict__ wsum,
    const float* __restrict__ sc,
    const float* __restrict__ nqg, const float* __restrict__ nqb,
    const float* __restrict__ nkg, const float* __restrict__ nkb,
    unsigned short* __restrict__ q2b, unsigned short* __restrict__ k2b,
    unsigned short* __restrict__ v2t) {
  __shared__ signed char As[128 * 128];
  __shared__ signed char Bs[128 * 128];
  const int t = threadIdx.x;
  const int brow = blockIdx.x * 128, bcol = blockIdx.y * 128;
  const int w = t >> 6, l = t & 63;
  const int lr = l & 15, lg = l >> 4;
  const int wr = (w >> 1) * 64, wc = (w & 1) * 64;
  i32x4 acc[4][4] = {};
  for (int kt = 0; kt < DIM; kt += 128) {
    __syncthreads();
    stage_i8(A + (size_t)brow * DIM + kt, DIM, As, w, l);
    stage_i8(Bw + (size_t)bcol * DIM + kt, DIM, Bs, w, l);
    __syncthreads();
#pragma unroll
    for (int ks = 0; ks < 2; ++ks) {
      i32x4 af[4], bfr[4];
#pragma unroll
      for (int i = 0; i < 4; ++i) {
        af[i] = *(const i32x4*)&As[(wr + i * 16 + lr) * 128 + ks * 64 + lg * 16];
        bfr[i] = *(const i32x4*)&Bs[(wc + i * 16 + lr) * 128 + ks * 64 + lg * 16];
      }
#pragma unroll
      for (int i = 0; i < 4; ++i)
#pragma unroll
        for (int j = 0; j < 4; ++j)
          acc[i][j] = MFMA_I8(af[i], bfr[j], acc[i][j]);
    }
  }
  // ---- epilogue: int->float with zero-point correction, scale, LN/quant ----
  const float sact = sc[0], zin = sc[1];
  float s_j[4], zw_j[4];
#pragma unroll
  for (int j = 0; j < 4; ++j) {
    const int col = bcol + wc + j * 16 + lr;
    s_j[j] = sact * colscale[col];
    zw_j[j] = zin * wsum[col];
  }
  f32x4 fac[4][4];
#pragma unroll
  for (int i = 0; i < 4; ++i)
#pragma unroll
    for (int j = 0; j < 4; ++j)
#pragma unroll
      for (int r = 0; r < 4; ++r)
        fac[i][j][r] = ((float)acc[i][j][r] - zw_j[j]) * s_j[j];

  const int seg = bcol / DIM;                 // 0=q,1=k,2=v
  const int h_ = ((bcol % DIM) + wc) / 64;    // head for this wave
  if (seg < 2) {
    const float* gp = seg ? nkg : nqg;
    const float* bp = seg ? nkb : nqb;
    const float aq_ = seg ? sc[4] : sc[2];
    const float zq_ = seg ? sc[5] : sc[3];
    float gj[4], bj[4];
#pragma unroll
    for (int j = 0; j < 4; ++j) { gj[j] = gp[j * 16 + lr]; bj[j] = bp[j * 16 + lr]; }
    unsigned short* dstb = seg ? k2b : q2b;
#pragma unroll
    for (int i = 0; i < 4; ++i)
#pragma unroll
      for (int r = 0; r < 4; ++r) {
        float sum = fac[i][0][r] + fac[i][1][r] + fac[i][2][r] + fac[i][3][r];
        sum += __shfl_xor(sum, 1); sum += __shfl_xor(sum, 2);
        sum += __shfl_xor(sum, 4); sum += __shfl_xor(sum, 8);
        float m = sum * (1.0f / 64.0f);
        float vs = 0.f;
#pragma unroll
        for (int j = 0; j < 4; ++j) { float d = fac[i][j][r] - m; vs += d * d; }
        vs += __shfl_xor(vs, 1); vs += __shfl_xor(vs, 2);
        vs += __shfl_xor(vs, 4); vs += __shfl_xor(vs, 8);
        float inv = 1.0f / sqrtf(vs * (1.0f / 64.0f) + 1e-5f);
        int row = brow + wr + i * 16 + lg * 4 + r;
        int b_ = row >> 10, n_ = row & (SEQ - 1);
        unsigned short* dst = dstb + (((size_t)(b_ * HEADS + h_) << 10) + n_) * HD;
#pragma unroll
        for (int j = 0; j < 4; ++j) {
          float yv = (fac[i][j][r] - m) * inv * gj[j] + bj[j];
          float qv = rintf(qclamp(yv / aq_ + zq_, -8.f, 7.f)) - zq_;
          dst[j * 16 + lr] = f2bf(qv);
        }
      }
  } else {
    const float av_ = sc[6], zv = sc[7];
#pragma unroll
    for (int i = 0; i < 4; ++i)
#pragma unroll
      for (int r = 0; r < 4; ++r) {
        int row = brow + wr + i * 16 + lg * 4 + r;
        int b_ = row >> 10, n_ = row & (SEQ - 1);
        unsigned short* dst = v2t + ((size_t)(b_ * HEADS + h_) << 16) + n_;
#pragma unroll
        for (int j = 0; j < 4; ++j) {
          float qv = rintf(qclamp(fac[i][j][r] / av_ + zv, -8.f, 7.f)) - zv;
          dst[(size_t)(j * 16 + lr) * SEQ] = f2bf(qv);
        }
      }
  }
}

// ---------------- proj GEMM (i8, BK=128; f32 out + bias) ----------------
__global__ __launch_bounds__(256) void k_gemm(
    const signed char* __restrict__ A, const signed char* __restrict__ Bw,
    float* __restrict__ out, const float* __restrict__ colscale,
    const float* __restrict__ wsum, const float* __restrict__ bias,
    const float* __restrict__ sc, int sact_idx, int zin_idx,
    int M, int Nt, int K) {
  __shared__ signed char As[128 * 128];
  __shared__ signed char Bs[128 * 128];
  const int t = threadIdx.x;
  const int brow = blockIdx.x * 128, bcol = blockIdx.y * 128;
  const int w = t >> 6, l = t & 63;
  const int lr = l & 15, lg = l >> 4;
  const int wr = (w >> 1) * 64, wc = (w & 1) * 64;
  i32x4 acc[4][4] = {};
  for (int kt = 0; kt < K; kt += 128) {
    __syncthreads();
    stage_i8(A + (size_t)brow * K + kt, K, As, w, l);
    stage_i8(Bw + (size_t)bcol * K + kt, K, Bs, w, l);
    __syncthreads();
#pragma unroll
    for (int ks = 0; ks < 2; ++ks) {
      i32x4 af[4], bfr[4];
#pragma unroll
      for (int i = 0; i < 4; ++i) {
        af[i] = *(const i32x4*)&As[(wr + i * 16 + lr) * 128 + ks * 64 + lg * 16];
        bfr[i] = *(const i32x4*)&Bs[(wc + i * 16 + lr) * 128 + ks * 64 + lg * 16];
      }
#pragma unroll
      for (int i = 0; i < 4; ++i)
#pragma unroll
        for (int j = 0; j < 4; ++j)
          acc[i][j] = MFMA_I8(af[i], bfr[j], acc[i][j]);
    }
  }
  const float sact = sc[sact_idx], zin = sc[zin_idx];
#pragma unroll
  for (int j = 0; j < 4; ++j) {
    const int col = bcol + wc + j * 16 + lr;
    const float s = sact * colscale[col];
    const float zw = zin * wsum[col];
    const float bb = bias ? bias[col] : 0.f;
#pragma unroll
    for (int i = 0; i < 4; ++i) {
      const int row0 = brow + wr + i * 16 + lg * 4;
#pragma unroll
      for (int r = 0; r < 4; ++r)
        out[(size_t)(row0 + r) * Nt + col] = ((float)acc[i][j][r] - zw) * s + bb;
    }
  }
}

// ---------------- fused attention v4 (unchanged structure; i8 x1q epilogue) ----
__global__ __launch_bounds__(256, 3) void k_attn(
    const unsigned short* __restrict__ q2b, const unsigned short* __restrict__ k2b,
    const unsigned short* __restrict__ v2t, signed char* __restrict__ x1q,
    const float* __restrict__ sc) {
  __shared__ unsigned short Ks[128][72];    // k rows x d (padded)
  __shared__ unsigned short Vs[64][136];    // d x k-tile (padded)
  __shared__ unsigned short Ps[4][32][40];  // per-wave quantized P, 32-col chunk
  const int t = threadIdx.x;
  const int w = t >> 6, l = t & 63;
  const int lr = l & 15, lg = l >> 4;
  // XCD-bijective swizzle: 768 = 8 * 96
  const int bid = (int)(blockIdx.x & 7) * 96 + (int)(blockIdx.x >> 3);
  const int bh = bid >> 3, qc = bid & 7;
  const unsigned short* Qg = q2b + (size_t)bh * (SEQ * HD);
  const unsigned short* Kg = k2b + (size_t)bh * (SEQ * HD);
  const unsigned short* Vg = v2t + (size_t)bh * (SEQ * HD);
  const float aq = sc[2], ak = sc[4], av_ = sc[6], aa = sc[8], za = sc[9];
  const float ap = sc[10], zpp = sc[11];
  const float sqk2 = aq * ak * 0.125f * 1.44269504f;  // fold log2(e)
  const float spv = aa * av_;
  const int qr0 = qc * 128 + w * 32;

  bf16x8 qf[2][2];
#pragma unroll
  for (int rt = 0; rt < 2; ++rt)
#pragma unroll
    for (int ks = 0; ks < 2; ++ks)
      qf[rt][ks] = *(const bf16x8*)(Qg + (size_t)(qr0 + rt * 16 + lr) * HD + ks * 32 + lg * 8);

  const int sr = t >> 1, sc0 = (t & 1) * 32;
  const int vr = t >> 2, vc0 = (t & 3) * 32;

  // ---- pass 1: denominator only
  float lacc[2][4] = {};
  for (int kt = 0; kt < SEQ; kt += 128) {
    const uint4* g = (const uint4*)(Kg + (size_t)(kt + sr) * HD + sc0);
    uint4 u0 = g[0], u1 = g[1], u2 = g[2], u3 = g[3];
    __syncthreads();
    { uint4* d = (uint4*)&Ks[sr][sc0]; d[0] = u0; d[1] = u1; d[2] = u2; d[3] = u3; }
    __syncthreads();
#pragma unroll
    for (int ct = 0; ct < 8; ++ct) {
      const int kl = ct * 16 + lr;
      bf16x8 kf0 = *(const bf16x8*)&Ks[kl][lg * 8];
      bf16x8 kf1 = *(const bf16x8*)&Ks[kl][32 + lg * 8];
#pragma unroll
      for (int rt = 0; rt < 2; ++rt) {
        f32x4 s4 = {0.f, 0.f, 0.f, 0.f};
        s4 = MFMA_B16(qf[rt][0], kf0, s4);
        s4 = MFMA_B16(qf[rt][1], kf1, s4);
#pragma unroll
        for (int r = 0; r < 4; ++r)
          lacc[rt][r] += __builtin_amdgcn_exp2f(s4[r] * sqk2);
      }
    }
  }
#pragma unroll
  for (int off = 1; off < 16; off <<= 1)
#pragma unroll
    for (int rt = 0; rt < 2; ++rt)
#pragma unroll
      for (int r = 0; r < 4; ++r) lacc[rt][r] += __shfl_xor(lacc[rt][r], off);
  float pinv[2][4];
#pragma unroll
  for (int rt = 0; rt < 2; ++rt)
#pragma unroll
    for (int r = 0; r < 4; ++r) pinv[rt][r] = 1.0f / (lacc[rt][r] * aa);

  // ---- pass 2: recompute S, quantize P (32-col chunks) interleaved with PV
  f32x4 oacc[2][4] = {};
  for (int kt = 0; kt < SEQ; kt += 128) {
    const uint4* gk = (const uint4*)(Kg + (size_t)(kt + sr) * HD + sc0);
    uint4 u0 = gk[0], u1 = gk[1], u2 = gk[2], u3 = gk[3];
    const uint4* gv = (const uint4*)(Vg + (size_t)vr * SEQ + kt + vc0);
    uint4 w0 = gv[0], w1 = gv[1], w2 = gv[2], w3 = gv[3];
    __syncthreads();
    { uint4* d = (uint4*)&Ks[sr][sc0]; d[0] = u0; d[1] = u1; d[2] = u2; d[3] = u3; }
    { uint4* d = (uint4*)&Vs[vr][vc0]; d[0] = w0; d[1] = w1; d[2] = w2; d[3] = w3; }
    __syncthreads();
#pragma unroll
    for (int q4 = 0; q4 < 4; ++q4) {
#pragma unroll
      for (int c2 = 0; c2 < 2; ++c2) {
        const int ct = q4 * 2 + c2;
        const int kl = ct * 16 + lr;
        bf16x8 kf0 = *(const bf16x8*)&Ks[kl][lg * 8];
        bf16x8 kf1 = *(const bf16x8*)&Ks[kl][32 + lg * 8];
#pragma unroll
        for (int rt = 0; rt < 2; ++rt) {
          f32x4 s4 = {0.f, 0.f, 0.f, 0.f};
          s4 = MFMA_B16(qf[rt][0], kf0, s4);
          s4 = MFMA_B16(qf[rt][1], kf1, s4);
#pragma unroll
          for (int r = 0; r < 4; ++r) {
            float e = __builtin_amdgcn_exp2f(s4[r] * sqk2);
            float p = fmaf(e, pinv[rt][r], za);
            float qv = rintf(qclamp(p, 0.f, 15.f)) - za;
            Ps[w][rt * 16 + lg * 4 + r][c2 * 16 + lr] = f2bf(qv);
          }
        }
      }
      bf16x8 vf[4], pf[2];
#pragma unroll
      for (int dt = 0; dt < 4; ++dt)
        vf[dt] = *(const bf16x8*)&Vs[dt * 16 + lr][q4 * 32 + lg * 8];
#pragma unroll
      for (int rt = 0; rt < 2; ++rt)
        pf[rt] = *(const bf16x8*)&Ps[w][rt * 16 + lr][lg * 8];
#pragma unroll
      for (int rt = 0; rt < 2; ++rt)
#pragma unroll
        for (int dt = 0; dt < 4; ++dt)
          oacc[rt][dt] = MFMA_B16(pf[rt], vf[dt], oacc[rt][dt]);
    }
  }
  // ---- epilogue: x1 int part -> i8 (proj corrects zero-point via wsum)
  const int b_ = bh / HEADS, h_ = bh % HEADS;
#pragma unroll
  for (int rt = 0; rt < 2; ++rt)
#pragma unroll
    for (int dt = 0; dt < 4; ++dt) {
      const int col = h_ * HD + dt * 16 + lr;
#pragma unroll
      for (int r = 0; r < 4; ++r) {
        const int qrow = qr0 + rt * 16 + lg * 4 + r;
        float x1v = oacc[rt][dt][r] * spv;
        int xi = (int)rintf(qclamp(x1v / ap + zpp, -8.f, 7.f));
        x1q[(size_t)(b_ * SEQ + qrow) * DIM + col] = (signed char)xi;
      }
    }
}

extern "C" void kernel_launch(void* const* d_in, const int* in_sizes, int n_in,
                              void* d_out, int out_size, void* d_ws, size_t ws_size,
                              hipStream_t stream) {
  const float* x0      = (const float*)d_in[0];
  const float* qkvw    = (const float*)d_in[1];
  const float* qkv_aw  = (const float*)d_in[2];
  const float* qkv_aa  = (const float*)d_in[3];
  const float* qkv_azp = (const float*)d_in[4];
  const float* nqg     = (const float*)d_in[5];
  const float* nqb     = (const float*)d_in[6];
  const float* nkg     = (const float*)d_in[7];
  const float* nkb     = (const float*)d_in[8];
  const float* q_a     = (const float*)d_in[9];
  const float* q_z     = (const float*)d_in[10];
  const float* k_a     = (const float*)d_in[11];
  const float* k_z     = (const float*)d_in[12];
  const float* v_a     = (const float*)d_in[13];
  const float* v_z     = (const float*)d_in[14];
  const float* at_a    = (const float*)d_in[15];
  const float* at_z    = (const float*)d_in[16];
  const float* pw      = (const float*)d_in[17];
  const float* pb      = (const float*)d_in[18];
  const float* p_aw    = (const float*)d_in[19];
  const float* p_aa    = (const float*)d_in[20];
  const float* p_azp   = (const float*)d_in[21];
  float* out = (float*)d_out;

  char* ws = (char*)d_ws;
  size_t off = 0;
  float* scal = (float*)(ws); off = 256;
  signed char* x0q  = (signed char*)(ws + off); off += (size_t)NTOK * DIM;
  signed char* qwq  = (signed char*)(ws + off); off += (size_t)TRIPLE * DIM;
  signed char* pwq  = (signed char*)(ws + off); off += (size_t)DIM * DIM;
  float* wsumQ      = (float*)(ws + off);       off += (size_t)TRIPLE * 4;
  float* wsumP      = (float*)(ws + off);       off += (size_t)DIM * 4;
  unsigned short* q2b = (unsigned short*)(ws + off); off += (size_t)BHTOT * SEQ * HD * 2;
  unsigned short* k2b = (unsigned short*)(ws + off); off += (size_t)BHTOT * SEQ * HD * 2;
  unsigned short* v2t = (unsigned short*)(ws + off); off += (size_t)BHTOT * SEQ * HD * 2;
  signed char* x1q  = (signed char*)(ws + off); off += (size_t)NTOK * DIM;

  k_prep<<<1, 256, 0, stream>>>(qkv_aa, qkv_azp, q_a, q_z, k_a, k_z, v_a, v_z,
                                at_a, at_z, p_aa, p_azp, scal);
  k_quant_act<<<(NTOK * DIM) / 1024, 256, 0, stream>>>(x0, x0q, scal, NTOK * DIM);
  k_quant_w<<<(TRIPLE * DIM) / 1024, 256, 0, stream>>>(qkvw, qkv_aw, qwq, TRIPLE * DIM, DIM);
  k_quant_w<<<(DIM * DIM) / 1024, 256, 0, stream>>>(pw, p_aw, pwq, DIM * DIM, DIM);
  k_wsum<<<TRIPLE / 4, 256, 0, stream>>>(qwq, wsumQ, DIM);
  k_wsum<<<DIM / 4, 256, 0, stream>>>(pwq, wsumP, DIM);
  k_gemm_qkv<<<dim3(NTOK / 128, TRIPLE / 128), 256, 0, stream>>>(
      x0q, qwq, qkv_aw, wsumQ, scal, nqg, nqb, nkg, nkb, q2b, k2b, v2t);
  k_attn<<<BHTOT * 8, 256, 0, stream>>>(q2b, k2b, v2t, x1q, scal);
  k_gemm<<<dim3(NTOK / 128, DIM / 128), 256, 0, stream>>>(
      x1q, pwq, out, p_aw, wsumP, pb, scal, 10, 11, NTOK, DIM, DIM);
}

// Round 10
// 267.250 us; speedup vs baseline: 1.8075x; 1.0120x over previous
//
#include <hip/hip_runtime.h>
#include <hip/hip_bf16.h>

#define HEADS 12
#define HD 64
#define DIM 768
#define SEQ 1024
#define NTOK 8192      // B*N
#define TRIPLE 2304    // 3*DIM
#define BHTOT 96       // B*HEADS

typedef __attribute__((ext_vector_type(8))) short bf16x8;
typedef __attribute__((ext_vector_type(4))) float f32x4;
typedef __attribute__((ext_vector_type(4))) int i32x4;

#define MFMA_B16(a, b, c) __builtin_amdgcn_mfma_f32_16x16x32_bf16((a), (b), (c), 0, 0, 0)
#define MFMA_I8(a, b, c) __builtin_amdgcn_mfma_i32_16x16x64_i8((a), (b), (c), 0, 0, 0)

__device__ __forceinline__ unsigned short f2bf(float f) {
  unsigned int u = __float_as_uint(f);
  unsigned int r = (u + 0x7fffu + ((u >> 16) & 1u)) >> 16;
  return (unsigned short)r;
}
__device__ __forceinline__ float qclamp(float v, float lo, float hi) {
  return fminf(fmaxf(v, lo), hi);
}

// ---------------- scalar prep ----------------
__device__ float block_mean(const float* p, int n, int rnd, float* red) {
  int t = threadIdx.x;
  float s = 0.f;
  for (int i = t; i < n; i += 256) { float v = p[i]; s += rnd ? rintf(v) : v; }
  red[t] = s;
  __syncthreads();
  for (int o = 128; o > 0; o >>= 1) { if (t < o) red[t] += red[t + o]; __syncthreads(); }
  float m = red[0] / (float)n;
  __syncthreads();
  return m;
}

__global__ __launch_bounds__(256) void k_prep(
    const float* qaa, const float* qzp, const float* qa, const float* qz,
    const float* ka, const float* kz, const float* va, const float* vz,
    const float* ata, const float* atz, const float* pa, const float* pz,
    float* sc) {
  __shared__ float red[256];
  float r0 = block_mean(qaa, 768, 0, red);
  float r1 = block_mean(qzp, 768, 1, red);
  float r2 = block_mean(qa, 12, 0, red);
  float r3 = block_mean(qz, 12, 1, red);
  float r4 = block_mean(ka, 12, 0, red);
  float r5 = block_mean(kz, 12, 1, red);
  float r6 = block_mean(va, 12, 0, red);
  float r7 = block_mean(vz, 12, 1, red);
  float r8 = block_mean(ata, 12, 0, red);
  float r9 = block_mean(atz, 12, 1, red);
  float r10 = block_mean(pa, 768, 0, red);
  float r11 = block_mean(pz, 768, 1, red);
  if (threadIdx.x == 0) {
    sc[0] = r0; sc[1] = r1; sc[2] = r2; sc[3] = r3; sc[4] = r4; sc[5] = r5;
    sc[6] = r6; sc[7] = r7; sc[8] = r8; sc[9] = r9; sc[10] = r10; sc[11] = r11;
  }
}

// ---------------- activation quantize: store INT part as i8 (z handled via wsum) ----------------
__global__ __launch_bounds__(256) void k_quant_act(
    const float* __restrict__ x, signed char* __restrict__ xq,
    const float* __restrict__ sc, int n) {
  int i = (blockIdx.x * 256 + threadIdx.x) * 4;
  if (i >= n) return;
  float a = sc[0], z = sc[1];
  float4 v = *(const float4*)(x + i);
  int b0 = (int)rintf(qclamp(v.x / a + z, -8.f, 7.f));
  int b1 = (int)rintf(qclamp(v.y / a + z, -8.f, 7.f));
  int b2 = (int)rintf(qclamp(v.z / a + z, -8.f, 7.f));
  int b3 = (int)rintf(qclamp(v.w / a + z, -8.f, 7.f));
  ((int*)xq)[i >> 2] = (b0 & 255) | ((b1 & 255) << 8) | ((b2 & 255) << 16) | (b3 << 24);
}

// ---------------- weight quantize -> i8 ----------------
__global__ __launch_bounds__(256) void k_quant_w(
    const float* __restrict__ w, const float* __restrict__ alpha,
    signed char* __restrict__ wq, int n, int K) {
  int i = (blockIdx.x * 256 + threadIdx.x) * 4;
  if (i >= n) return;
  float a = alpha[i / K];
  float4 v = *(const float4*)(w + i);
  int b0 = (int)rintf(qclamp(v.x / a, -8.f, 7.f));
  int b1 = (int)rintf(qclamp(v.y / a, -8.f, 7.f));
  int b2 = (int)rintf(qclamp(v.z / a, -8.f, 7.f));
  int b3 = (int)rintf(qclamp(v.w / a, -8.f, 7.f));
  ((int*)wq)[i >> 2] = (b0 & 255) | ((b1 & 255) << 8) | ((b2 & 255) << 16) | (b3 << 24);
}

// ---------------- per-out-row weight int sums (zero-point correction) ----------------
__global__ __launch_bounds__(256) void k_wsum(
    const signed char* __restrict__ wq, float* __restrict__ s, int K) {
  const int w = threadIdx.x >> 6, l = threadIdx.x & 63;
  const int row = blockIdx.x * 4 + w;
  const int* rp = (const int*)(wq + (size_t)row * K);
  int acc = 0;
  for (int idx = l; idx < K / 4; idx += 64) {
    int u = rp[idx];
    acc += (int)(signed char)u + (int)(signed char)(u >> 8) +
           (int)(signed char)(u >> 16) + (int)(signed char)(u >> 24);
  }
#pragma unroll
  for (int off = 32; off > 0; off >>= 1) acc += __shfl_xor(acc, off);
  if (l == 0) s[row] = (float)acc;
}

// ---- global->LDS direct staging of a 128x128 i8 tile ----
// wave w, inst j covers rows w*32+j*8..+8; lane l -> row +(l>>3), byte col (l&7)*16.
__device__ __forceinline__ void stage_i8(
    const signed char* __restrict__ g, int ldk,
    signed char* lds, int wv, int l) {
#pragma unroll
  for (int j = 0; j < 4; ++j) {
    __builtin_amdgcn_global_load_lds(
        (const __attribute__((address_space(1))) void*)(
            g + (size_t)(wv * 32 + j * 8 + (l >> 3)) * ldk + (l & 7) * 16),
        (__attribute__((address_space(3))) void*)(lds + wv * 4096 + j * 1024),
        16, 0, 0);
  }
}

// ---------------- qkv GEMM (i8, BK=128, 2-phase dbuf) + fused LN/quant epilogue ----------------
__global__ __launch_bounds__(256) void k_gemm_qkv(
    const signed char* __restrict__ A, const signed char* __restrict__ Bw,
    const float* __restrict__ colscale, const float* __restrict__ wsum,
    const float* __restrict__ sc,
    const float* __restrict__ nqg, const float* __restrict__ nqb,
    const float* __restrict__ nkg, const float* __restrict__ nkb,
    unsigned short* __restrict__ q2b, unsigned short* __restrict__ k2b,
    unsigned short* __restrict__ v2t) {
  __shared__ signed char As[2][128 * 128];
  __shared__ signed char Bs[2][128 * 128];
  const int t = threadIdx.x;
  const int brow = blockIdx.x * 128, bcol = blockIdx.y * 128;
  const int w = t >> 6, l = t & 63;
  const int lr = l & 15, lg = l >> 4;
  const int wr = (w >> 1) * 64, wc = (w & 1) * 64;
  i32x4 acc[4][4] = {};

  auto compute = [&](const signed char* sa, const signed char* sb) {
#pragma unroll
    for (int ks = 0; ks < 2; ++ks) {
      i32x4 af[4], bfr[4];
#pragma unroll
      for (int i = 0; i < 4; ++i) {
        af[i] = *(const i32x4*)&sa[(wr + i * 16 + lr) * 128 + ks * 64 + lg * 16];
        bfr[i] = *(const i32x4*)&sb[(wc + i * 16 + lr) * 128 + ks * 64 + lg * 16];
      }
#pragma unroll
      for (int i = 0; i < 4; ++i)
#pragma unroll
        for (int j = 0; j < 4; ++j)
          acc[i][j] = MFMA_I8(af[i], bfr[j], acc[i][j]);
    }
  };

  const int nt = DIM / 128;  // 6
  stage_i8(A + (size_t)brow * DIM, DIM, As[0], w, l);
  stage_i8(Bw + (size_t)bcol * DIM, DIM, Bs[0], w, l);
  __syncthreads();
  int cur = 0;
  for (int kt = 0; kt < nt - 1; ++kt) {
    // issue next tile's loads FIRST -> they fly during this tile's MFMA
    stage_i8(A + (size_t)brow * DIM + (kt + 1) * 128, DIM, As[cur ^ 1], w, l);
    stage_i8(Bw + (size_t)bcol * DIM + (kt + 1) * 128, DIM, Bs[cur ^ 1], w, l);
    compute(As[cur], Bs[cur]);
    __syncthreads();  // drains vmcnt(0): prefetch had the MFMA phase to land
    cur ^= 1;
  }
  compute(As[cur], Bs[cur]);

  // ---- epilogue: int->float with zero-point correction, scale, LN/quant ----
  const float sact = sc[0], zin = sc[1];
  float s_j[4], zw_j[4];
#pragma unroll
  for (int j = 0; j < 4; ++j) {
    const int col = bcol + wc + j * 16 + lr;
    s_j[j] = sact * colscale[col];
    zw_j[j] = zin * wsum[col];
  }
  f32x4 fac[4][4];
#pragma unroll
  for (int i = 0; i < 4; ++i)
#pragma unroll
    for (int j = 0; j < 4; ++j)
#pragma unroll
      for (int r = 0; r < 4; ++r)
        fac[i][j][r] = ((float)acc[i][j][r] - zw_j[j]) * s_j[j];

  const int seg = bcol / DIM;                 // 0=q,1=k,2=v
  const int h_ = ((bcol % DIM) + wc) / 64;    // head for this wave
  if (seg < 2) {
    const float* gp = seg ? nkg : nqg;
    const float* bp = seg ? nkb : nqb;
    const float aq_ = seg ? sc[4] : sc[2];
    const float zq_ = seg ? sc[5] : sc[3];
    float gj[4], bj[4];
#pragma unroll
    for (int j = 0; j < 4; ++j) { gj[j] = gp[j * 16 + lr]; bj[j] = bp[j * 16 + lr]; }
    unsigned short* dstb = seg ? k2b : q2b;
#pragma unroll
    for (int i = 0; i < 4; ++i)
#pragma unroll
      for (int r = 0; r < 4; ++r) {
        float sum = fac[i][0][r] + fac[i][1][r] + fac[i][2][r] + fac[i][3][r];
        sum += __shfl_xor(sum, 1); sum += __shfl_xor(sum, 2);
        sum += __shfl_xor(sum, 4); sum += __shfl_xor(sum, 8);
        float m = sum * (1.0f / 64.0f);
        float vs = 0.f;
#pragma unroll
        for (int j = 0; j < 4; ++j) { float d = fac[i][j][r] - m; vs += d * d; }
        vs += __shfl_xor(vs, 1); vs += __shfl_xor(vs, 2);
        vs += __shfl_xor(vs, 4); vs += __shfl_xor(vs, 8);
        float inv = 1.0f / sqrtf(vs * (1.0f / 64.0f) + 1e-5f);
        int row = brow + wr + i * 16 + lg * 4 + r;
        int b_ = row >> 10, n_ = row & (SEQ - 1);
        unsigned short* dst = dstb + (((size_t)(b_ * HEADS + h_) << 10) + n_) * HD;
#pragma unroll
        for (int j = 0; j < 4; ++j) {
          float yv = (fac[i][j][r] - m) * inv * gj[j] + bj[j];
          float qv = rintf(qclamp(yv / aq_ + zq_, -8.f, 7.f)) - zq_;
          dst[j * 16 + lr] = f2bf(qv);
        }
      }
  } else {
    const float av_ = sc[6], zv = sc[7];
#pragma unroll
    for (int i = 0; i < 4; ++i)
#pragma unroll
      for (int r = 0; r < 4; ++r) {
        int row = brow + wr + i * 16 + lg * 4 + r;
        int b_ = row >> 10, n_ = row & (SEQ - 1);
        unsigned short* dst = v2t + ((size_t)(b_ * HEADS + h_) << 16) + n_;
#pragma unroll
        for (int j = 0; j < 4; ++j) {
          float qv = rintf(qclamp(fac[i][j][r] / av_ + zv, -8.f, 7.f)) - zv;
          dst[(size_t)(j * 16 + lr) * SEQ] = f2bf(qv);
        }
      }
  }
}

// ---------------- proj GEMM (i8, BK=128, 2-phase dbuf; f32 out + bias) ----------------
__global__ __launch_bounds__(256) void k_gemm(
    const signed char* __restrict__ A, const signed char* __restrict__ Bw,
    float* __restrict__ out, const float* __restrict__ colscale,
    const float* __restrict__ wsum, const float* __restrict__ bias,
    const float* __restrict__ sc, int sact_idx, int zin_idx,
    int M, int Nt, int K) {
  __shared__ signed char As[2][128 * 128];
  __shared__ signed char Bs[2][128 * 128];
  const int t = threadIdx.x;
  const int brow = blockIdx.x * 128, bcol = blockIdx.y * 128;
  const int w = t >> 6, l = t & 63;
  const int lr = l & 15, lg = l >> 4;
  const int wr = (w >> 1) * 64, wc = (w & 1) * 64;
  i32x4 acc[4][4] = {};

  auto compute = [&](const signed char* sa, const signed char* sb) {
#pragma unroll
    for (int ks = 0; ks < 2; ++ks) {
      i32x4 af[4], bfr[4];
#pragma unroll
      for (int i = 0; i < 4; ++i) {
        af[i] = *(const i32x4*)&sa[(wr + i * 16 + lr) * 128 + ks * 64 + lg * 16];
        bfr[i] = *(const i32x4*)&sb[(wc + i * 16 + lr) * 128 + ks * 64 + lg * 16];
      }
#pragma unroll
      for (int i = 0; i < 4; ++i)
#pragma unroll
        for (int j = 0; j < 4; ++j)
          acc[i][j] = MFMA_I8(af[i], bfr[j], acc[i][j]);
    }
  };

  const int nt = K / 128;
  stage_i8(A + (size_t)brow * K, K, As[0], w, l);
  stage_i8(Bw + (size_t)bcol * K, K, Bs[0], w, l);
  __syncthreads();
  int cur = 0;
  for (int kt = 0; kt < nt - 1; ++kt) {
    stage_i8(A + (size_t)brow * K + (kt + 1) * 128, K, As[cur ^ 1], w, l);
    stage_i8(Bw + (size_t)bcol * K + (kt + 1) * 128, K, Bs[cur ^ 1], w, l);
    compute(As[cur], Bs[cur]);
    __syncthreads();
    cur ^= 1;
  }
  compute(As[cur], Bs[cur]);

  const float sact = sc[sact_idx], zin = sc[zin_idx];
#pragma unroll
  for (int j = 0; j < 4; ++j) {
    const int col = bcol + wc + j * 16 + lr;
    const float s = sact * colscale[col];
    const float zw = zin * wsum[col];
    const float bb = bias ? bias[col] : 0.f;
#pragma unroll
    for (int i = 0; i < 4; ++i) {
      const int row0 = brow + wr + i * 16 + lg * 4;
#pragma unroll
      for (int r = 0; r < 4; ++r)
        out[(size_t)(row0 + r) * Nt + col] = ((float)acc[i][j][r] - zw) * s + bb;
    }
  }
}

// ---------------- fused attention v4 (unchanged, measured 74.5us; i8 x1q epilogue) ----
__global__ __launch_bounds__(256, 3) void k_attn(
    const unsigned short* __restrict__ q2b, const unsigned short* __restrict__ k2b,
    const unsigned short* __restrict__ v2t, signed char* __restrict__ x1q,
    const float* __restrict__ sc) {
  __shared__ unsigned short Ks[128][72];    // k rows x d (padded)
  __shared__ unsigned short Vs[64][136];    // d x k-tile (padded)
  __shared__ unsigned short Ps[4][32][40];  // per-wave quantized P, 32-col chunk
  const int t = threadIdx.x;
  const int w = t >> 6, l = t & 63;
  const int lr = l & 15, lg = l >> 4;
  // XCD-bijective swizzle: 768 = 8 * 96
  const int bid = (int)(blockIdx.x & 7) * 96 + (int)(blockIdx.x >> 3);
  const int bh = bid >> 3, qc = bid & 7;
  const unsigned short* Qg = q2b + (size_t)bh * (SEQ * HD);
  const unsigned short* Kg = k2b + (size_t)bh * (SEQ * HD);
  const unsigned short* Vg = v2t + (size_t)bh * (SEQ * HD);
  const float aq = sc[2], ak = sc[4], av_ = sc[6], aa = sc[8], za = sc[9];
  const float ap = sc[10], zpp = sc[11];
  const float sqk2 = aq * ak * 0.125f * 1.44269504f;  // fold log2(e)
  const float spv = aa * av_;
  const int qr0 = qc * 128 + w * 32;

  bf16x8 qf[2][2];
#pragma unroll
  for (int rt = 0; rt < 2; ++rt)
#pragma unroll
    for (int ks = 0; ks < 2; ++ks)
      qf[rt][ks] = *(const bf16x8*)(Qg + (size_t)(qr0 + rt * 16 + lr) * HD + ks * 32 + lg * 8);

  const int sr = t >> 1, sc0 = (t & 1) * 32;
  const int vr = t >> 2, vc0 = (t & 3) * 32;

  // ---- pass 1: denominator only
  float lacc[2][4] = {};
  for (int kt = 0; kt < SEQ; kt += 128) {
    const uint4* g = (const uint4*)(Kg + (size_t)(kt + sr) * HD + sc0);
    uint4 u0 = g[0], u1 = g[1], u2 = g[2], u3 = g[3];
    __syncthreads();
    { uint4* d = (uint4*)&Ks[sr][sc0]; d[0] = u0; d[1] = u1; d[2] = u2; d[3] = u3; }
    __syncthreads();
#pragma unroll
    for (int ct = 0; ct < 8; ++ct) {
      const int kl = ct * 16 + lr;
      bf16x8 kf0 = *(const bf16x8*)&Ks[kl][lg * 8];
      bf16x8 kf1 = *(const bf16x8*)&Ks[kl][32 + lg * 8];
#pragma unroll
      for (int rt = 0; rt < 2; ++rt) {
        f32x4 s4 = {0.f, 0.f, 0.f, 0.f};
        s4 = MFMA_B16(qf[rt][0], kf0, s4);
        s4 = MFMA_B16(qf[rt][1], kf1, s4);
#pragma unroll
        for (int r = 0; r < 4; ++r)
          lacc[rt][r] += __builtin_amdgcn_exp2f(s4[r] * sqk2);
      }
    }
  }
#pragma unroll
  for (int off = 1; off < 16; off <<= 1)
#pragma unroll
    for (int rt = 0; rt < 2; ++rt)
#pragma unroll
      for (int r = 0; r < 4; ++r) lacc[rt][r] += __shfl_xor(lacc[rt][r], off);
  float pinv[2][4];
#pragma unroll
  for (int rt = 0; rt < 2; ++rt)
#pragma unroll
    for (int r = 0; r < 4; ++r) pinv[rt][r] = 1.0f / (lacc[rt][r] * aa);

  // ---- pass 2: recompute S, quantize P (32-col chunks) interleaved with PV
  f32x4 oacc[2][4] = {};
  for (int kt = 0; kt < SEQ; kt += 128) {
    const uint4* gk = (const uint4*)(Kg + (size_t)(kt + sr) * HD + sc0);
    uint4 u0 = gk[0], u1 = gk[1], u2 = gk[2], u3 = gk[3];
    const uint4* gv = (const uint4*)(Vg + (size_t)vr * SEQ + kt + vc0);
    uint4 w0 = gv[0], w1 = gv[1], w2 = gv[2], w3 = gv[3];
    __syncthreads();
    { uint4* d = (uint4*)&Ks[sr][sc0]; d[0] = u0; d[1] = u1; d[2] = u2; d[3] = u3; }
    { uint4* d = (uint4*)&Vs[vr][vc0]; d[0] = w0; d[1] = w1; d[2] = w2; d[3] = w3; }
    __syncthreads();
#pragma unroll
    for (int q4 = 0; q4 < 4; ++q4) {
#pragma unroll
      for (int c2 = 0; c2 < 2; ++c2) {
        const int ct = q4 * 2 + c2;
        const int kl = ct * 16 + lr;
        bf16x8 kf0 = *(const bf16x8*)&Ks[kl][lg * 8];
        bf16x8 kf1 = *(const bf16x8*)&Ks[kl][32 + lg * 8];
#pragma unroll
        for (int rt = 0; rt < 2; ++rt) {
          f32x4 s4 = {0.f, 0.f, 0.f, 0.f};
          s4 = MFMA_B16(qf[rt][0], kf0, s4);
          s4 = MFMA_B16(qf[rt][1], kf1, s4);
#pragma unroll
          for (int r = 0; r < 4; ++r) {
            float e = __builtin_amdgcn_exp2f(s4[r] * sqk2);
            float p = fmaf(e, pinv[rt][r], za);
            float qv = rintf(qclamp(p, 0.f, 15.f)) - za;
            Ps[w][rt * 16 + lg * 4 + r][c2 * 16 + lr] = f2bf(qv);
          }
        }
      }
      bf16x8 vf[4], pf[2];
#pragma unroll
      for (int dt = 0; dt < 4; ++dt)
        vf[dt] = *(const bf16x8*)&Vs[dt * 16 + lr][q4 * 32 + lg * 8];
#pragma unroll
      for (int rt = 0; rt < 2; ++rt)
        pf[rt] = *(const bf16x8*)&Ps[w][rt * 16 + lr][lg * 8];
#pragma unroll
      for (int rt = 0; rt < 2; ++rt)
#pragma unroll
        for (int dt = 0; dt < 4; ++dt)
          oacc[rt][dt] = MFMA_B16(pf[rt], vf[dt], oacc[rt][dt]);
    }
  }
  // ---- epilogue: x1 int part -> i8 (proj corrects zero-point via wsum)
  const int b_ = bh / HEADS, h_ = bh % HEADS;
#pragma unroll
  for (int rt = 0; rt < 2; ++rt)
#pragma unroll
    for (int dt = 0; dt < 4; ++dt) {
      const int col = h_ * HD + dt * 16 + lr;
#pragma unroll
      for (int r = 0; r < 4; ++r) {
        const int qrow = qr0 + rt * 16 + lg * 4 + r;
        float x1v = oacc[rt][dt][r] * spv;
        int xi = (int)rintf(qclamp(x1v / ap + zpp, -8.f, 7.f));
        x1q[(size_t)(b_ * SEQ + qrow) * DIM + col] = (signed char)xi;
      }
    }
}

extern "C" void kernel_launch(void* const* d_in, const int* in_sizes, int n_in,
                              void* d_out, int out_size, void* d_ws, size_t ws_size,
                              hipStream_t stream) {
  const float* x0      = (const float*)d_in[0];
  const float* qkvw    = (const float*)d_in[1];
  const float* qkv_aw  = (const float*)d_in[2];
  const float* qkv_aa  = (const float*)d_in[3];
  const float* qkv_azp = (const float*)d_in[4];
  const float* nqg     = (const float*)d_in[5];
  const float* nqb     = (const float*)d_in[6];
  const float* nkg     = (const float*)d_in[7];
  const float* nkb     = (const float*)d_in[8];
  const float* q_a     = (const float*)d_in[9];
  const float* q_z     = (const float*)d_in[10];
  const float* k_a     = (const float*)d_in[11];
  const float* k_z     = (const float*)d_in[12];
  const float* v_a     = (const float*)d_in[13];
  const float* v_z     = (const float*)d_in[14];
  const float* at_a    = (const float*)d_in[15];
  const float* at_z    = (const float*)d_in[16];
  const float* pw      = (const float*)d_in[17];
  const float* pb      = (const float*)d_in[18];
  const float* p_aw    = (const float*)d_in[19];
  const float* p_aa    = (const float*)d_in[20];
  const float* p_azp   = (const float*)d_in[21];
  float* out = (float*)d_out;

  char* ws = (char*)d_ws;
  size_t off = 0;
  float* scal = (float*)(ws); off = 256;
  signed char* x0q  = (signed char*)(ws + off); off += (size_t)NTOK * DIM;
  signed char* qwq  = (signed char*)(ws + off); off += (size_t)TRIPLE * DIM;
  signed char* pwq  = (signed char*)(ws + off); off += (size_t)DIM * DIM;
  float* wsumQ      = (float*)(ws + off);       off += (size_t)TRIPLE * 4;
  float* wsumP      = (float*)(ws + off);       off += (size_t)DIM * 4;
  unsigned short* q2b = (unsigned short*)(ws + off); off += (size_t)BHTOT * SEQ * HD * 2;
  unsigned short* k2b = (unsigned short*)(ws + off); off += (size_t)BHTOT * SEQ * HD * 2;
  unsigned short* v2t = (unsigned short*)(ws + off); off += (size_t)BHTOT * SEQ * HD * 2;
  signed char* x1q  = (signed char*)(ws + off); off += (size_t)NTOK * DIM;

  k_prep<<<1, 256, 0, stream>>>(qkv_aa, qkv_azp, q_a, q_z, k_a, k_z, v_a, v_z,
                                at_a, at_z, p_aa, p_azp, scal);
  k_quant_act<<<(NTOK * DIM) / 1024, 256, 0, stream>>>(x0, x0q, scal, NTOK * DIM);
  k_quant_w<<<(TRIPLE * DIM) / 1024, 256, 0, stream>>>(qkvw, qkv_aw, qwq, TRIPLE * DIM, DIM);
  k_quant_w<<<(DIM * DIM) / 1024, 256, 0, stream>>>(pw, p_aw, pwq, DIM * DIM, DIM);
  k_wsum<<<TRIPLE / 4, 256, 0, stream>>>(qwq, wsumQ, DIM);
  k_wsum<<<DIM / 4, 256, 0, stream>>>(pwq, wsumP, DIM);
  k_gemm_qkv<<<dim3(NTOK / 128, TRIPLE / 128), 256, 0, stream>>>(
      x0q, qwq, qkv_aw, wsumQ, scal, nqg, nqb, nkg, nkb, q2b, k2b, v2t);
  k_attn<<<BHTOT * 8, 256, 0, stream>>>(q2b, k2b, v2t, x1q, scal);
  k_gemm<<<dim3(NTOK / 128, DIM / 128), 256, 0, stream>>>(
      x1q, pwq, out, p_aw, wsumP, pb, scal, 10, 11, NTOK, DIM, DIM);
}

// Round 11
// 258.932 us; speedup vs baseline: 1.8656x; 1.0321x over previous
//
#include <hip/hip_runtime.h>
#include <hip/hip_bf16.h>

#define HEADS 12
#define HD 64
#define DIM 768
#define SEQ 1024
#define NTOK 8192      // B*N
#define TRIPLE 2304    // 3*DIM
#define BHTOT 96       // B*HEADS

typedef __attribute__((ext_vector_type(8))) short bf16x8;
typedef __attribute__((ext_vector_type(4))) float f32x4;
typedef __attribute__((ext_vector_type(4))) int i32x4;

#define MFMA_B16(a, b, c) __builtin_amdgcn_mfma_f32_16x16x32_bf16((a), (b), (c), 0, 0, 0)
#define MFMA_I8(a, b, c) __builtin_amdgcn_mfma_i32_16x16x64_i8((a), (b), (c), 0, 0, 0)

__device__ __forceinline__ unsigned short f2bf(float f) {
  unsigned int u = __float_as_uint(f);
  unsigned int r = (u + 0x7fffu + ((u >> 16) & 1u)) >> 16;
  return (unsigned short)r;
}
__device__ __forceinline__ float qclamp(float v, float lo, float hi) {
  return fminf(fmaxf(v, lo), hi);
}

// ---------------- scalar prep ----------------
__device__ float block_mean(const float* p, int n, int rnd, float* red) {
  int t = threadIdx.x;
  float s = 0.f;
  for (int i = t; i < n; i += 256) { float v = p[i]; s += rnd ? rintf(v) : v; }
  red[t] = s;
  __syncthreads();
  for (int o = 128; o > 0; o >>= 1) { if (t < o) red[t] += red[t + o]; __syncthreads(); }
  float m = red[0] / (float)n;
  __syncthreads();
  return m;
}

__global__ __launch_bounds__(256) void k_prep(
    const float* qaa, const float* qzp, const float* qa, const float* qz,
    const float* ka, const float* kz, const float* va, const float* vz,
    const float* ata, const float* atz, const float* pa, const float* pz,
    float* sc) {
  __shared__ float red[256];
  float r0 = block_mean(qaa, 768, 0, red);
  float r1 = block_mean(qzp, 768, 1, red);
  float r2 = block_mean(qa, 12, 0, red);
  float r3 = block_mean(qz, 12, 1, red);
  float r4 = block_mean(ka, 12, 0, red);
  float r5 = block_mean(kz, 12, 1, red);
  float r6 = block_mean(va, 12, 0, red);
  float r7 = block_mean(vz, 12, 1, red);
  float r8 = block_mean(ata, 12, 0, red);
  float r9 = block_mean(atz, 12, 1, red);
  float r10 = block_mean(pa, 768, 0, red);
  float r11 = block_mean(pz, 768, 1, red);
  if (threadIdx.x == 0) {
    sc[0] = r0; sc[1] = r1; sc[2] = r2; sc[3] = r3; sc[4] = r4; sc[5] = r5;
    sc[6] = r6; sc[7] = r7; sc[8] = r8; sc[9] = r9; sc[10] = r10; sc[11] = r11;
  }
}

// ---------------- activation quantize: store INT part as i8 (z handled via wsum) ----------------
__global__ __launch_bounds__(256) void k_quant_act(
    const float* __restrict__ x, signed char* __restrict__ xq,
    const float* __restrict__ sc, int n) {
  int i = (blockIdx.x * 256 + threadIdx.x) * 4;
  if (i >= n) return;
  float a = sc[0], z = sc[1];
  float4 v = *(const float4*)(x + i);
  int b0 = (int)rintf(qclamp(v.x / a + z, -8.f, 7.f));
  int b1 = (int)rintf(qclamp(v.y / a + z, -8.f, 7.f));
  int b2 = (int)rintf(qclamp(v.z / a + z, -8.f, 7.f));
  int b3 = (int)rintf(qclamp(v.w / a + z, -8.f, 7.f));
  ((int*)xq)[i >> 2] = (b0 & 255) | ((b1 & 255) << 8) | ((b2 & 255) << 16) | (b3 << 24);
}

// ---------------- weight quantize -> i8 ----------------
__global__ __launch_bounds__(256) void k_quant_w(
    const float* __restrict__ w, const float* __restrict__ alpha,
    signed char* __restrict__ wq, int n, int K) {
  int i = (blockIdx.x * 256 + threadIdx.x) * 4;
  if (i >= n) return;
  float a = alpha[i / K];
  float4 v = *(const float4*)(w + i);
  int b0 = (int)rintf(qclamp(v.x / a, -8.f, 7.f));
  int b1 = (int)rintf(qclamp(v.y / a, -8.f, 7.f));
  int b2 = (int)rintf(qclamp(v.z / a, -8.f, 7.f));
  int b3 = (int)rintf(qclamp(v.w / a, -8.f, 7.f));
  ((int*)wq)[i >> 2] = (b0 & 255) | ((b1 & 255) << 8) | ((b2 & 255) << 16) | (b3 << 24);
}

// ---------------- per-out-row weight int sums (zero-point correction) ----------------
__global__ __launch_bounds__(256) void k_wsum(
    const signed char* __restrict__ wq, float* __restrict__ s, int K) {
  const int w = threadIdx.x >> 6, l = threadIdx.x & 63;
  const int row = blockIdx.x * 4 + w;
  const int* rp = (const int*)(wq + (size_t)row * K);
  int acc = 0;
  for (int idx = l; idx < K / 4; idx += 64) {
    int u = rp[idx];
    acc += (int)(signed char)u + (int)(signed char)(u >> 8) +
           (int)(signed char)(u >> 16) + (int)(signed char)(u >> 24);
  }
#pragma unroll
  for (int off = 32; off > 0; off >>= 1) acc += __shfl_xor(acc, off);
  if (l == 0) s[row] = (float)acc;
}

// ---- global->LDS staging: 128 rows (4 insts/wave) and 64 rows (2 insts/wave) ----
__device__ __forceinline__ void stage_i8(
    const signed char* __restrict__ g, int ldk,
    signed char* lds, int wv, int l) {
#pragma unroll
  for (int j = 0; j < 4; ++j) {
    __builtin_amdgcn_global_load_lds(
        (const __attribute__((address_space(1))) void*)(
            g + (size_t)(wv * 32 + j * 8 + (l >> 3)) * ldk + (l & 7) * 16),
        (__attribute__((address_space(3))) void*)(lds + wv * 4096 + j * 1024),
        16, 0, 0);
  }
}
__device__ __forceinline__ void stage_i8_64(
    const signed char* __restrict__ g, int ldk,
    signed char* lds, int wv, int l) {
#pragma unroll
  for (int j = 0; j < 2; ++j) {
    __builtin_amdgcn_global_load_lds(
        (const __attribute__((address_space(1))) void*)(
            g + (size_t)(wv * 16 + j * 8 + (l >> 3)) * ldk + (l & 7) * 16),
        (__attribute__((address_space(3))) void*)(lds + wv * 2048 + j * 1024),
        16, 0, 0);
  }
}

// ---------------- qkv GEMM (i8, BK=128, 2-phase dbuf) + fused LN/quant epilogue ----------------
// V segment: quantize -> LDS transpose tile T[d][n] -> coalesced 256B-per-instr stores.
__global__ __launch_bounds__(256) void k_gemm_qkv(
    const signed char* __restrict__ A, const signed char* __restrict__ Bw,
    const float* __restrict__ colscale, const float* __restrict__ wsum,
    const float* __restrict__ sc,
    const float* __restrict__ nqg, const float* __restrict__ nqb,
    const float* __restrict__ nkg, const float* __restrict__ nkb,
    unsigned short* __restrict__ q2b, unsigned short* __restrict__ k2b,
    unsigned short* __restrict__ v2t) {
  __shared__ __align__(16) char smem[65536];
  signed char (*As)[16384] = (signed char(*)[16384])smem;
  signed char (*Bs)[16384] = (signed char(*)[16384])(smem + 32768);
  unsigned short (*T)[132] = (unsigned short(*)[132])smem;  // reused post-loop (V seg)
  const int t = threadIdx.x;
  const int brow = blockIdx.x * 128, bcol = blockIdx.y * 128;
  const int w = t >> 6, l = t & 63;
  const int lr = l & 15, lg = l >> 4;
  const int wr = (w >> 1) * 64, wc = (w & 1) * 64;
  i32x4 acc[4][4] = {};

  auto compute = [&](const signed char* sa, const signed char* sb) {
#pragma unroll
    for (int ks = 0; ks < 2; ++ks) {
      i32x4 af[4], bfr[4];
#pragma unroll
      for (int i = 0; i < 4; ++i) {
        af[i] = *(const i32x4*)&sa[(wr + i * 16 + lr) * 128 + ks * 64 + lg * 16];
        bfr[i] = *(const i32x4*)&sb[(wc + i * 16 + lr) * 128 + ks * 64 + lg * 16];
      }
#pragma unroll
      for (int i = 0; i < 4; ++i)
#pragma unroll
        for (int j = 0; j < 4; ++j)
          acc[i][j] = MFMA_I8(af[i], bfr[j], acc[i][j]);
    }
  };

  const int nt = DIM / 128;  // 6
  stage_i8(A + (size_t)brow * DIM, DIM, As[0], w, l);
  stage_i8(Bw + (size_t)bcol * DIM, DIM, Bs[0], w, l);
  __syncthreads();
  int cur = 0;
  for (int kt = 0; kt < nt - 1; ++kt) {
    stage_i8(A + (size_t)brow * DIM + (kt + 1) * 128, DIM, As[cur ^ 1], w, l);
    stage_i8(Bw + (size_t)bcol * DIM + (kt + 1) * 128, DIM, Bs[cur ^ 1], w, l);
    compute(As[cur], Bs[cur]);
    __syncthreads();
    cur ^= 1;
  }
  compute(As[cur], Bs[cur]);

  // ---- epilogue: int->float with zero-point correction, scale, LN/quant ----
  const float sact = sc[0], zin = sc[1];
  float s_j[4], zw_j[4];
#pragma unroll
  for (int j = 0; j < 4; ++j) {
    const int col = bcol + wc + j * 16 + lr;
    s_j[j] = sact * colscale[col];
    zw_j[j] = zin * wsum[col];
  }
  f32x4 fac[4][4];
#pragma unroll
  for (int i = 0; i < 4; ++i)
#pragma unroll
    for (int j = 0; j < 4; ++j)
#pragma unroll
      for (int r = 0; r < 4; ++r)
        fac[i][j][r] = ((float)acc[i][j][r] - zw_j[j]) * s_j[j];

  const int seg = bcol / DIM;                 // 0=q,1=k,2=v
  const int h0 = ((bcol % DIM) + wc) / 64;    // head for this wave (q/k path)
  if (seg < 2) {
    const float* gp = seg ? nkg : nqg;
    const float* bp = seg ? nkb : nqb;
    const float aq_ = seg ? sc[4] : sc[2];
    const float zq_ = seg ? sc[5] : sc[3];
    float gj[4], bj[4];
#pragma unroll
    for (int j = 0; j < 4; ++j) { gj[j] = gp[j * 16 + lr]; bj[j] = bp[j * 16 + lr]; }
    unsigned short* dstb = seg ? k2b : q2b;
#pragma unroll
    for (int i = 0; i < 4; ++i)
#pragma unroll
      for (int r = 0; r < 4; ++r) {
        float sum = fac[i][0][r] + fac[i][1][r] + fac[i][2][r] + fac[i][3][r];
        sum += __shfl_xor(sum, 1); sum += __shfl_xor(sum, 2);
        sum += __shfl_xor(sum, 4); sum += __shfl_xor(sum, 8);
        float m = sum * (1.0f / 64.0f);
        float vs = 0.f;
#pragma unroll
        for (int j = 0; j < 4; ++j) { float d = fac[i][j][r] - m; vs += d * d; }
        vs += __shfl_xor(vs, 1); vs += __shfl_xor(vs, 2);
        vs += __shfl_xor(vs, 4); vs += __shfl_xor(vs, 8);
        float inv = 1.0f / sqrtf(vs * (1.0f / 64.0f) + 1e-5f);
        int row = brow + wr + i * 16 + lg * 4 + r;
        int b_ = row >> 10, n_ = row & (SEQ - 1);
        unsigned short* dst = dstb + (((size_t)(b_ * HEADS + h0) << 10) + n_) * HD;
#pragma unroll
        for (int j = 0; j < 4; ++j) {
          float yv = (fac[i][j][r] - m) * inv * gj[j] + bj[j];
          float qv = rintf(qclamp(yv / aq_ + zq_, -8.f, 7.f)) - zq_;
          dst[j * 16 + lr] = f2bf(qv);
        }
      }
  } else {
    // ---- V: quantize -> LDS tile T[d(128)][n(132 pad)] -> coalesced write
    const float av_ = sc[6], zv = sc[7];
    __syncthreads();  // all waves done reading As/Bs; smem becomes T
#pragma unroll
    for (int i = 0; i < 4; ++i)
#pragma unroll
      for (int r = 0; r < 4; ++r) {
        const int rowl = wr + i * 16 + lg * 4 + r;  // block-local n
#pragma unroll
        for (int j = 0; j < 4; ++j) {
          float qv = rintf(qclamp(fac[i][j][r] / av_ + zv, -8.f, 7.f)) - zv;
          T[wc + j * 16 + lr][rowl] = f2bf(qv);
        }
      }
    __syncthreads();
    const int b_ = brow >> 10, n0 = brow & (SEQ - 1);
    const int hbase = (bcol % DIM) / 64;  // first head of this block's 128 cols
#pragma unroll
    for (int it = 0; it < 32; ++it) {
      const int dcol = w * 32 + it;               // block-local d (0..127)
      const int h_ = hbase + (dcol >> 6);
      const int d_ = dcol & 63;
      unsigned int val = *(const unsigned int*)&T[dcol][2 * l];
      *(unsigned int*)(v2t + ((size_t)(b_ * HEADS + h_) << 16) +
                       (size_t)d_ * SEQ + n0 + 2 * l) = val;
    }
  }
}

// ---------------- proj GEMM (i8, BK=128, 64x128 tile, 2-phase dbuf; f32 out + bias) ----------------
__global__ __launch_bounds__(256) void k_gemm(
    const signed char* __restrict__ A, const signed char* __restrict__ Bw,
    float* __restrict__ out, const float* __restrict__ colscale,
    const float* __restrict__ wsum, const float* __restrict__ bias,
    const float* __restrict__ sc, int sact_idx, int zin_idx,
    int M, int Nt, int K) {
  __shared__ signed char As[2][64 * 128];
  __shared__ signed char Bs[2][128 * 128];
  const int t = threadIdx.x;
  const int brow = blockIdx.x * 64, bcol = blockIdx.y * 128;
  const int w = t >> 6, l = t & 63;
  const int lr = l & 15, lg = l >> 4;
  const int wr = (w >> 1) * 32, wc = (w & 1) * 64;
  i32x4 acc[2][4] = {};

  auto compute = [&](const signed char* sa, const signed char* sb) {
#pragma unroll
    for (int ks = 0; ks < 2; ++ks) {
      i32x4 af[2], bfr[4];
#pragma unroll
      for (int i = 0; i < 2; ++i)
        af[i] = *(const i32x4*)&sa[(wr + i * 16 + lr) * 128 + ks * 64 + lg * 16];
#pragma unroll
      for (int j = 0; j < 4; ++j)
        bfr[j] = *(const i32x4*)&sb[(wc + j * 16 + lr) * 128 + ks * 64 + lg * 16];
#pragma unroll
      for (int i = 0; i < 2; ++i)
#pragma unroll
        for (int j = 0; j < 4; ++j)
          acc[i][j] = MFMA_I8(af[i], bfr[j], acc[i][j]);
    }
  };

  const int nt = K / 128;
  stage_i8_64(A + (size_t)brow * K, K, As[0], w, l);
  stage_i8(Bw + (size_t)bcol * K, K, Bs[0], w, l);
  __syncthreads();
  int cur = 0;
  for (int kt = 0; kt < nt - 1; ++kt) {
    stage_i8_64(A + (size_t)brow * K + (kt + 1) * 128, K, As[cur ^ 1], w, l);
    stage_i8(Bw + (size_t)bcol * K + (kt + 1) * 128, K, Bs[cur ^ 1], w, l);
    compute(As[cur], Bs[cur]);
    __syncthreads();
    cur ^= 1;
  }
  compute(As[cur], Bs[cur]);

  const float sact = sc[sact_idx], zin = sc[zin_idx];
#pragma unroll
  for (int j = 0; j < 4; ++j) {
    const int col = bcol + wc + j * 16 + lr;
    const float s = sact * colscale[col];
    const float zw = zin * wsum[col];
    const float bb = bias ? bias[col] : 0.f;
#pragma unroll
    for (int i = 0; i < 2; ++i) {
      const int row0 = brow + wr + i * 16 + lg * 4;
#pragma unroll
      for (int r = 0; r < 4; ++r)
        out[(size_t)(row0 + r) * Nt + col] = ((float)acc[i][j][r] - zw) * s + bb;
    }
  }
}

// ---------------- fused attention v4 (unchanged, measured 73.5us; i8 x1q epilogue) ----
__global__ __launch_bounds__(256, 3) void k_attn(
    const unsigned short* __restrict__ q2b, const unsigned short* __restrict__ k2b,
    const unsigned short* __restrict__ v2t, signed char* __restrict__ x1q,
    const float* __restrict__ sc) {
  __shared__ unsigned short Ks[128][72];    // k rows x d (padded)
  __shared__ unsigned short Vs[64][136];    // d x k-tile (padded)
  __shared__ unsigned short Ps[4][32][40];  // per-wave quantized P, 32-col chunk
  const int t = threadIdx.x;
  const int w = t >> 6, l = t & 63;
  const int lr = l & 15, lg = l >> 4;
  // XCD-bijective swizzle: 768 = 8 * 96
  const int bid = (int)(blockIdx.x & 7) * 96 + (int)(blockIdx.x >> 3);
  const int bh = bid >> 3, qc = bid & 7;
  const unsigned short* Qg = q2b + (size_t)bh * (SEQ * HD);
  const unsigned short* Kg = k2b + (size_t)bh * (SEQ * HD);
  const unsigned short* Vg = v2t + (size_t)bh * (SEQ * HD);
  const float aq = sc[2], ak = sc[4], av_ = sc[6], aa = sc[8], za = sc[9];
  const float ap = sc[10], zpp = sc[11];
  const float sqk2 = aq * ak * 0.125f * 1.44269504f;  // fold log2(e)
  const float spv = aa * av_;
  const int qr0 = qc * 128 + w * 32;

  bf16x8 qf[2][2];
#pragma unroll
  for (int rt = 0; rt < 2; ++rt)
#pragma unroll
    for (int ks = 0; ks < 2; ++ks)
      qf[rt][ks] = *(const bf16x8*)(Qg + (size_t)(qr0 + rt * 16 + lr) * HD + ks * 32 + lg * 8);

  const int sr = t >> 1, sc0 = (t & 1) * 32;
  const int vr = t >> 2, vc0 = (t & 3) * 32;

  // ---- pass 1: denominator only
  float lacc[2][4] = {};
  for (int kt = 0; kt < SEQ; kt += 128) {
    const uint4* g = (const uint4*)(Kg + (size_t)(kt + sr) * HD + sc0);
    uint4 u0 = g[0], u1 = g[1], u2 = g[2], u3 = g[3];
    __syncthreads();
    { uint4* d = (uint4*)&Ks[sr][sc0]; d[0] = u0; d[1] = u1; d[2] = u2; d[3] = u3; }
    __syncthreads();
#pragma unroll
    for (int ct = 0; ct < 8; ++ct) {
      const int kl = ct * 16 + lr;
      bf16x8 kf0 = *(const bf16x8*)&Ks[kl][lg * 8];
      bf16x8 kf1 = *(const bf16x8*)&Ks[kl][32 + lg * 8];
#pragma unroll
      for (int rt = 0; rt < 2; ++rt) {
        f32x4 s4 = {0.f, 0.f, 0.f, 0.f};
        s4 = MFMA_B16(qf[rt][0], kf0, s4);
        s4 = MFMA_B16(qf[rt][1], kf1, s4);
#pragma unroll
        for (int r = 0; r < 4; ++r)
          lacc[rt][r] += __builtin_amdgcn_exp2f(s4[r] * sqk2);
      }
    }
  }
#pragma unroll
  for (int off = 1; off < 16; off <<= 1)
#pragma unroll
    for (int rt = 0; rt < 2; ++rt)
#pragma unroll
      for (int r = 0; r < 4; ++r) lacc[rt][r] += __shfl_xor(lacc[rt][r], off);
  float pinv[2][4];
#pragma unroll
  for (int rt = 0; rt < 2; ++rt)
#pragma unroll
    for (int r = 0; r < 4; ++r) pinv[rt][r] = 1.0f / (lacc[rt][r] * aa);

  // ---- pass 2: recompute S, quantize P (32-col chunks) interleaved with PV
  f32x4 oacc[2][4] = {};
  for (int kt = 0; kt < SEQ; kt += 128) {
    const uint4* gk = (const uint4*)(Kg + (size_t)(kt + sr) * HD + sc0);
    uint4 u0 = gk[0], u1 = gk[1], u2 = gk[2], u3 = gk[3];
    const uint4* gv = (const uint4*)(Vg + (size_t)vr * SEQ + kt + vc0);
    uint4 w0 = gv[0], w1 = gv[1], w2 = gv[2], w3 = gv[3];
    __syncthreads();
    { uint4* d = (uint4*)&Ks[sr][sc0]; d[0] = u0; d[1] = u1; d[2] = u2; d[3] = u3; }
    { uint4* d = (uint4*)&Vs[vr][vc0]; d[0] = w0; d[1] = w1; d[2] = w2; d[3] = w3; }
    __syncthreads();
#pragma unroll
    for (int q4 = 0; q4 < 4; ++q4) {
#pragma unroll
      for (int c2 = 0; c2 < 2; ++c2) {
        const int ct = q4 * 2 + c2;
        const int kl = ct * 16 + lr;
        bf16x8 kf0 = *(const bf16x8*)&Ks[kl][lg * 8];
        bf16x8 kf1 = *(const bf16x8*)&Ks[kl][32 + lg * 8];
#pragma unroll
        for (int rt = 0; rt < 2; ++rt) {
          f32x4 s4 = {0.f, 0.f, 0.f, 0.f};
          s4 = MFMA_B16(qf[rt][0], kf0, s4);
          s4 = MFMA_B16(qf[rt][1], kf1, s4);
#pragma unroll
          for (int r = 0; r < 4; ++r) {
            float e = __builtin_amdgcn_exp2f(s4[r] * sqk2);
            float p = fmaf(e, pinv[rt][r], za);
            float qv = rintf(qclamp(p, 0.f, 15.f)) - za;
            Ps[w][rt * 16 + lg * 4 + r][c2 * 16 + lr] = f2bf(qv);
          }
        }
      }
      bf16x8 vf[4], pf[2];
#pragma unroll
      for (int dt = 0; dt < 4; ++dt)
        vf[dt] = *(const bf16x8*)&Vs[dt * 16 + lr][q4 * 32 + lg * 8];
#pragma unroll
      for (int rt = 0; rt < 2; ++rt)
        pf[rt] = *(const bf16x8*)&Ps[w][rt * 16 + lr][lg * 8];
#pragma unroll
      for (int rt = 0; rt < 2; ++rt)
#pragma unroll
        for (int dt = 0; dt < 4; ++dt)
          oacc[rt][dt] = MFMA_B16(pf[rt], vf[dt], oacc[rt][dt]);
    }
  }
  // ---- epilogue: x1 int part -> i8 (proj corrects zero-point via wsum)
  const int b_ = bh / HEADS, h_ = bh % HEADS;
#pragma unroll
  for (int rt = 0; rt < 2; ++rt)
#pragma unroll
    for (int dt = 0; dt < 4; ++dt) {
      const int col = h_ * HD + dt * 16 + lr;
#pragma unroll
      for (int r = 0; r < 4; ++r) {
        const int qrow = qr0 + rt * 16 + lg * 4 + r;
        float x1v = oacc[rt][dt][r] * spv;
        int xi = (int)rintf(qclamp(x1v / ap + zpp, -8.f, 7.f));
        x1q[(size_t)(b_ * SEQ + qrow) * DIM + col] = (signed char)xi;
      }
    }
}

extern "C" void kernel_launch(void* const* d_in, const int* in_sizes, int n_in,
                              void* d_out, int out_size, void* d_ws, size_t ws_size,
                              hipStream_t stream) {
  const float* x0      = (const float*)d_in[0];
  const float* qkvw    = (const float*)d_in[1];
  const float* qkv_aw  = (const float*)d_in[2];
  const float* qkv_aa  = (const float*)d_in[3];
  const float* qkv_azp = (const float*)d_in[4];
  const float* nqg     = (const float*)d_in[5];
  const float* nqb     = (const float*)d_in[6];
  const float* nkg     = (const float*)d_in[7];
  const float* nkb     = (const float*)d_in[8];
  const float* q_a     = (const float*)d_in[9];
  const float* q_z     = (const float*)d_in[10];
  const float* k_a     = (const float*)d_in[11];
  const float* k_z     = (const float*)d_in[12];
  const float* v_a     = (const float*)d_in[13];
  const float* v_z     = (const float*)d_in[14];
  const float* at_a    = (const float*)d_in[15];
  const float* at_z    = (const float*)d_in[16];
  const float* pw      = (const float*)d_in[17];
  const float* pb      = (const float*)d_in[18];
  const float* p_aw    = (const float*)d_in[19];
  const float* p_aa    = (const float*)d_in[20];
  const float* p_azp   = (const float*)d_in[21];
  float* out = (float*)d_out;

  char* ws = (char*)d_ws;
  size_t off = 0;
  float* scal = (float*)(ws); off = 256;
  signed char* x0q  = (signed char*)(ws + off); off += (size_t)NTOK * DIM;
  signed char* qwq  = (signed char*)(ws + off); off += (size_t)TRIPLE * DIM;
  signed char* pwq  = (signed char*)(ws + off); off += (size_t)DIM * DIM;
  float* wsumQ      = (float*)(ws + off);       off += (size_t)TRIPLE * 4;
  float* wsumP      = (float*)(ws + off);       off += (size_t)DIM * 4;
  unsigned short* q2b = (unsigned short*)(ws + off); off += (size_t)BHTOT * SEQ * HD * 2;
  unsigned short* k2b = (unsigned short*)(ws + off); off += (size_t)BHTOT * SEQ * HD * 2;
  unsigned short* v2t = (unsigned short*)(ws + off); off += (size_t)BHTOT * SEQ * HD * 2;
  signed char* x1q  = (signed char*)(ws + off); off += (size_t)NTOK * DIM;

  k_prep<<<1, 256, 0, stream>>>(qkv_aa, qkv_azp, q_a, q_z, k_a, k_z, v_a, v_z,
                                at_a, at_z, p_aa, p_azp, scal);
  k_quant_act<<<(NTOK * DIM) / 1024, 256, 0, stream>>>(x0, x0q, scal, NTOK * DIM);
  k_quant_w<<<(TRIPLE * DIM) / 1024, 256, 0, stream>>>(qkvw, qkv_aw, qwq, TRIPLE * DIM, DIM);
  k_quant_w<<<(DIM * DIM) / 1024, 256, 0, stream>>>(pw, p_aw, pwq, DIM * DIM, DIM);
  k_wsum<<<TRIPLE / 4, 256, 0, stream>>>(qwq, wsumQ, DIM);
  k_wsum<<<DIM / 4, 256, 0, stream>>>(pwq, wsumP, DIM);
  k_gemm_qkv<<<dim3(NTOK / 128, TRIPLE / 128), 256, 0, stream>>>(
      x0q, qwq, qkv_aw, wsumQ, scal, nqg, nqb, nkg, nkb, q2b, k2b, v2t);
  k_attn<<<BHTOT * 8, 256, 0, stream>>>(q2b, k2b, v2t, x1q, scal);
  k_gemm<<<dim3(NTOK / 64, DIM / 128), 256, 0, stream>>>(
      x1q, pwq, out, p_aw, wsumP, pb, scal, 10, 11, NTOK, DIM, DIM);
}

// Round 12
// 255.960 us; speedup vs baseline: 1.8872x; 1.0116x over previous
//
#include <hip/hip_runtime.h>
#include <hip/hip_bf16.h>

#define HEADS 12
#define HD 64
#define DIM 768
#define SEQ 1024
#define NTOK 8192      // B*N
#define TRIPLE 2304    // 3*DIM
#define BHTOT 96       // B*HEADS

typedef __attribute__((ext_vector_type(8))) short bf16x8;
typedef __attribute__((ext_vector_type(4))) float f32x4;
typedef __attribute__((ext_vector_type(4))) int i32x4;

#define MFMA_B16(a, b, c) __builtin_amdgcn_mfma_f32_16x16x32_bf16((a), (b), (c), 0, 0, 0)
#define MFMA_I8(a, b, c) __builtin_amdgcn_mfma_i32_16x16x64_i8((a), (b), (c), 0, 0, 0)

__device__ __forceinline__ unsigned short f2bf(float f) {
  unsigned int u = __float_as_uint(f);
  unsigned int r = (u + 0x7fffu + ((u >> 16) & 1u)) >> 16;
  return (unsigned short)r;
}
__device__ __forceinline__ float qclamp(float v, float lo, float hi) {
  return fminf(fmaxf(v, lo), hi);
}

// ---------------- scalar prep ----------------
__device__ float block_mean(const float* p, int n, int rnd, float* red) {
  int t = threadIdx.x;
  float s = 0.f;
  for (int i = t; i < n; i += 256) { float v = p[i]; s += rnd ? rintf(v) : v; }
  red[t] = s;
  __syncthreads();
  for (int o = 128; o > 0; o >>= 1) { if (t < o) red[t] += red[t + o]; __syncthreads(); }
  float m = red[0] / (float)n;
  __syncthreads();
  return m;
}

__global__ __launch_bounds__(256) void k_prep(
    const float* qaa, const float* qzp, const float* qa, const float* qz,
    const float* ka, const float* kz, const float* va, const float* vz,
    const float* ata, const float* atz, const float* pa, const float* pz,
    float* sc) {
  __shared__ float red[256];
  float r0 = block_mean(qaa, 768, 0, red);
  float r1 = block_mean(qzp, 768, 1, red);
  float r2 = block_mean(qa, 12, 0, red);
  float r3 = block_mean(qz, 12, 1, red);
  float r4 = block_mean(ka, 12, 0, red);
  float r5 = block_mean(kz, 12, 1, red);
  float r6 = block_mean(va, 12, 0, red);
  float r7 = block_mean(vz, 12, 1, red);
  float r8 = block_mean(ata, 12, 0, red);
  float r9 = block_mean(atz, 12, 1, red);
  float r10 = block_mean(pa, 768, 0, red);
  float r11 = block_mean(pz, 768, 1, red);
  if (threadIdx.x == 0) {
    sc[0] = r0; sc[1] = r1; sc[2] = r2; sc[3] = r3; sc[4] = r4; sc[5] = r5;
    sc[6] = r6; sc[7] = r7; sc[8] = r8; sc[9] = r9; sc[10] = r10; sc[11] = r11;
  }
}

// ---------------- activation quantize: store INT part as i8 (z via wsum) ----------------
__global__ __launch_bounds__(256) void k_quant_act(
    const float* __restrict__ x, signed char* __restrict__ xq,
    const float* __restrict__ sc, int n) {
  int i = (blockIdx.x * 256 + threadIdx.x) * 4;
  if (i >= n) return;
  float a = sc[0], z = sc[1];
  float4 v = *(const float4*)(x + i);
  int b0 = (int)rintf(qclamp(v.x / a + z, -8.f, 7.f));
  int b1 = (int)rintf(qclamp(v.y / a + z, -8.f, 7.f));
  int b2 = (int)rintf(qclamp(v.z / a + z, -8.f, 7.f));
  int b3 = (int)rintf(qclamp(v.w / a + z, -8.f, 7.f));
  ((int*)xq)[i >> 2] = (b0 & 255) | ((b1 & 255) << 8) | ((b2 & 255) << 16) | (b3 << 24);
}

// ---------------- weight quantize -> i8, fused per-row wsum (wave per row) ----------------
__global__ __launch_bounds__(256) void k_quant_w_ws(
    const float* __restrict__ w, const float* __restrict__ alpha,
    signed char* __restrict__ wq, float* __restrict__ wsum) {
  const int wv = threadIdx.x >> 6, l = threadIdx.x & 63;
  const int row = blockIdx.x * 4 + wv;
  const float a = alpha[row];
  const float* src = w + (size_t)row * DIM;
  int* dst = (int*)(wq + (size_t)row * DIM);
  int s = 0;
#pragma unroll
  for (int j = 0; j < 3; ++j) {
    const int idx = j * 64 + l;  // 192 int4-groups per 768-row
    float4 v = *(const float4*)(src + idx * 4);
    int b0 = (int)rintf(qclamp(v.x / a, -8.f, 7.f));
    int b1 = (int)rintf(qclamp(v.y / a, -8.f, 7.f));
    int b2 = (int)rintf(qclamp(v.z / a, -8.f, 7.f));
    int b3 = (int)rintf(qclamp(v.w / a, -8.f, 7.f));
    dst[idx] = (b0 & 255) | ((b1 & 255) << 8) | ((b2 & 255) << 16) | (b3 << 24);
    s += b0 + b1 + b2 + b3;
  }
#pragma unroll
  for (int off = 32; off > 0; off >>= 1) s += __shfl_xor(s, off);
  if (l == 0) wsum[row] = (float)s;
}

// ---- global->LDS staging helpers (linear dest, m97 pattern) ----
// 128 rows x 64B (BK=64 tile): 2 insts/wave; lane l -> row wv*32+j*16+(l>>2), col (l&3)*16
__device__ __forceinline__ void stage128x64_i8(
    const signed char* __restrict__ g, int ldk,
    signed char* lds, int wv, int l) {
#pragma unroll
  for (int j = 0; j < 2; ++j) {
    __builtin_amdgcn_global_load_lds(
        (const __attribute__((address_space(1))) void*)(
            g + (size_t)(wv * 32 + j * 16 + (l >> 2)) * ldk + (l & 3) * 16),
        (__attribute__((address_space(3))) void*)(lds + wv * 2048 + j * 1024),
        16, 0, 0);
  }
}
// 64 rows x 128B (BK=128 tile): 2 insts/wave; lane l -> row wv*16+j*8+(l>>3), col (l&7)*16
__device__ __forceinline__ void stage64x128_i8(
    const signed char* __restrict__ g, int ldk,
    signed char* lds, int wv, int l) {
#pragma unroll
  for (int j = 0; j < 2; ++j) {
    __builtin_amdgcn_global_load_lds(
        (const __attribute__((address_space(1))) void*)(
            g + (size_t)(wv * 16 + j * 8 + (l >> 3)) * ldk + (l & 7) * 16),
        (__attribute__((address_space(3))) void*)(lds + wv * 2048 + j * 1024),
        16, 0, 0);
  }
}

// ---------------- qkv GEMM (i8, BK=64, 2-phase dbuf, 32KB LDS -> 4 blocks/CU) ----------------
// + fused LN/quant epilogue; V segment via LDS-transpose coalesced store.
__global__ __launch_bounds__(256) void k_gemm_qkv(
    const signed char* __restrict__ A, const signed char* __restrict__ Bw,
    const float* __restrict__ colscale, const float* __restrict__ wsum,
    const float* __restrict__ sc,
    const float* __restrict__ nqg, const float* __restrict__ nqb,
    const float* __restrict__ nkg, const float* __restrict__ nkb,
    unsigned short* __restrict__ q2b, unsigned short* __restrict__ k2b,
    unsigned short* __restrict__ v2t) {
  __shared__ __align__(16) char smem[33792];
  signed char (*As)[8192] = (signed char(*)[8192])smem;
  signed char (*Bs)[8192] = (signed char(*)[8192])(smem + 16384);
  unsigned short (*T)[132] = (unsigned short(*)[132])smem;  // V-seg overlay
  const int t = threadIdx.x;
  const int brow = blockIdx.x * 128, bcol = blockIdx.y * 128;
  const int w = t >> 6, l = t & 63;
  const int lr = l & 15, lg = l >> 4;
  const int wr = (w >> 1) * 64, wc = (w & 1) * 64;
  i32x4 acc[4][4] = {};

  auto compute = [&](const signed char* sa, const signed char* sb) {
    i32x4 af[4], bfr[4];
#pragma unroll
    for (int i = 0; i < 4; ++i) {
      af[i] = *(const i32x4*)&sa[(wr + i * 16 + lr) * 64 + lg * 16];
      bfr[i] = *(const i32x4*)&sb[(wc + i * 16 + lr) * 64 + lg * 16];
    }
#pragma unroll
    for (int i = 0; i < 4; ++i)
#pragma unroll
      for (int j = 0; j < 4; ++j)
        acc[i][j] = MFMA_I8(af[i], bfr[j], acc[i][j]);
  };

  const int nt = DIM / 64;  // 12
  stage128x64_i8(A + (size_t)brow * DIM, DIM, As[0], w, l);
  stage128x64_i8(Bw + (size_t)bcol * DIM, DIM, Bs[0], w, l);
  __syncthreads();
  int cur = 0;
  for (int kt = 0; kt < nt - 1; ++kt) {
    stage128x64_i8(A + (size_t)brow * DIM + (kt + 1) * 64, DIM, As[cur ^ 1], w, l);
    stage128x64_i8(Bw + (size_t)bcol * DIM + (kt + 1) * 64, DIM, Bs[cur ^ 1], w, l);
    compute(As[cur], Bs[cur]);
    __syncthreads();
    cur ^= 1;
  }
  compute(As[cur], Bs[cur]);

  // ---- epilogue: int->float with zero-point correction, scale, LN/quant ----
  const float sact = sc[0], zin = sc[1];
  float s_j[4], zw_j[4];
#pragma unroll
  for (int j = 0; j < 4; ++j) {
    const int col = bcol + wc + j * 16 + lr;
    s_j[j] = sact * colscale[col];
    zw_j[j] = zin * wsum[col];
  }
  f32x4 fac[4][4];
#pragma unroll
  for (int i = 0; i < 4; ++i)
#pragma unroll
    for (int j = 0; j < 4; ++j)
#pragma unroll
      for (int r = 0; r < 4; ++r)
        fac[i][j][r] = ((float)acc[i][j][r] - zw_j[j]) * s_j[j];

  const int seg = bcol / DIM;                 // 0=q,1=k,2=v
  const int h0 = ((bcol % DIM) + wc) / 64;    // head for this wave (q/k path)
  if (seg < 2) {
    const float* gp = seg ? nkg : nqg;
    const float* bp = seg ? nkb : nqb;
    const float aq_ = seg ? sc[4] : sc[2];
    const float zq_ = seg ? sc[5] : sc[3];
    float gj[4], bj[4];
#pragma unroll
    for (int j = 0; j < 4; ++j) { gj[j] = gp[j * 16 + lr]; bj[j] = bp[j * 16 + lr]; }
    unsigned short* dstb = seg ? k2b : q2b;
#pragma unroll
    for (int i = 0; i < 4; ++i)
#pragma unroll
      for (int r = 0; r < 4; ++r) {
        float sum = fac[i][0][r] + fac[i][1][r] + fac[i][2][r] + fac[i][3][r];
        sum += __shfl_xor(sum, 1); sum += __shfl_xor(sum, 2);
        sum += __shfl_xor(sum, 4); sum += __shfl_xor(sum, 8);
        float m = sum * (1.0f / 64.0f);
        float vs = 0.f;
#pragma unroll
        for (int j = 0; j < 4; ++j) { float d = fac[i][j][r] - m; vs += d * d; }
        vs += __shfl_xor(vs, 1); vs += __shfl_xor(vs, 2);
        vs += __shfl_xor(vs, 4); vs += __shfl_xor(vs, 8);
        float inv = 1.0f / sqrtf(vs * (1.0f / 64.0f) + 1e-5f);
        int row = brow + wr + i * 16 + lg * 4 + r;
        int b_ = row >> 10, n_ = row & (SEQ - 1);
        unsigned short* dst = dstb + (((size_t)(b_ * HEADS + h0) << 10) + n_) * HD;
#pragma unroll
        for (int j = 0; j < 4; ++j) {
          float yv = (fac[i][j][r] - m) * inv * gj[j] + bj[j];
          float qv = rintf(qclamp(yv / aq_ + zq_, -8.f, 7.f)) - zq_;
          dst[j * 16 + lr] = f2bf(qv);
        }
      }
  } else {
    // ---- V: quantize -> LDS tile T[d(128)][n(132 pad)] -> coalesced write
    const float av_ = sc[6], zv = sc[7];
    __syncthreads();  // all waves done reading As/Bs; smem becomes T
#pragma unroll
    for (int i = 0; i < 4; ++i)
#pragma unroll
      for (int r = 0; r < 4; ++r) {
        const int rowl = wr + i * 16 + lg * 4 + r;  // block-local n
#pragma unroll
        for (int j = 0; j < 4; ++j) {
          float qv = rintf(qclamp(fac[i][j][r] / av_ + zv, -8.f, 7.f)) - zv;
          T[wc + j * 16 + lr][rowl] = f2bf(qv);
        }
      }
    __syncthreads();
    const int b_ = brow >> 10, n0 = brow & (SEQ - 1);
    const int hbase = (bcol % DIM) / 64;  // first head of this block's 128 cols
#pragma unroll
    for (int it = 0; it < 32; ++it) {
      const int dcol = w * 32 + it;               // block-local d (0..127)
      const int h_ = hbase + (dcol >> 6);
      const int d_ = dcol & 63;
      unsigned int val = *(const unsigned int*)&T[dcol][2 * l];
      *(unsigned int*)(v2t + ((size_t)(b_ * HEADS + h_) << 16) +
                       (size_t)d_ * SEQ + n0 + 2 * l) = val;
    }
  }
}

// ---------------- proj GEMM (i8, 64x64 tile, BK=128, 2-phase dbuf; f32 out + bias) ----------------
// 4 waves 2x2, each 32x32; 32KB LDS -> 5 blocks/CU; grid 1536.
__global__ __launch_bounds__(256) void k_gemm(
    const signed char* __restrict__ A, const signed char* __restrict__ Bw,
    float* __restrict__ out, const float* __restrict__ colscale,
    const float* __restrict__ wsum, const float* __restrict__ bias,
    const float* __restrict__ sc, int sact_idx, int zin_idx,
    int M, int Nt, int K) {
  __shared__ signed char As[2][64 * 128];
  __shared__ signed char Bs[2][64 * 128];
  const int t = threadIdx.x;
  const int brow = blockIdx.x * 64, bcol = blockIdx.y * 64;
  const int w = t >> 6, l = t & 63;
  const int lr = l & 15, lg = l >> 4;
  const int wr = (w >> 1) * 32, wc = (w & 1) * 32;
  i32x4 acc[2][2] = {};

  auto compute = [&](const signed char* sa, const signed char* sb) {
#pragma unroll
    for (int ks = 0; ks < 2; ++ks) {
      i32x4 af[2], bfr[2];
#pragma unroll
      for (int i = 0; i < 2; ++i) {
        af[i] = *(const i32x4*)&sa[(wr + i * 16 + lr) * 128 + ks * 64 + lg * 16];
        bfr[i] = *(const i32x4*)&sb[(wc + i * 16 + lr) * 128 + ks * 64 + lg * 16];
      }
#pragma unroll
      for (int i = 0; i < 2; ++i)
#pragma unroll
        for (int j = 0; j < 2; ++j)
          acc[i][j] = MFMA_I8(af[i], bfr[j], acc[i][j]);
    }
  };

  const int nt = K / 128;
  stage64x128_i8(A + (size_t)brow * K, K, As[0], w, l);
  stage64x128_i8(Bw + (size_t)bcol * K, K, Bs[0], w, l);
  __syncthreads();
  int cur = 0;
  for (int kt = 0; kt < nt - 1; ++kt) {
    stage64x128_i8(A + (size_t)brow * K + (kt + 1) * 128, K, As[cur ^ 1], w, l);
    stage64x128_i8(Bw + (size_t)bcol * K + (kt + 1) * 128, K, Bs[cur ^ 1], w, l);
    compute(As[cur], Bs[cur]);
    __syncthreads();
    cur ^= 1;
  }
  compute(As[cur], Bs[cur]);

  const float sact = sc[sact_idx], zin = sc[zin_idx];
#pragma unroll
  for (int j = 0; j < 2; ++j) {
    const int col = bcol + wc + j * 16 + lr;
    const float s = sact * colscale[col];
    const float zw = zin * wsum[col];
    const float bb = bias ? bias[col] : 0.f;
#pragma unroll
    for (int i = 0; i < 2; ++i) {
      const int row0 = brow + wr + i * 16 + lg * 4;
#pragma unroll
      for (int r = 0; r < 4; ++r)
        out[(size_t)(row0 + r) * Nt + col] = ((float)acc[i][j][r] - zw) * s + bb;
    }
  }
}

// ---------------- fused attention v4 (unchanged, measured 73.5us; i8 x1q epilogue) ----
__global__ __launch_bounds__(256, 3) void k_attn(
    const unsigned short* __restrict__ q2b, const unsigned short* __restrict__ k2b,
    const unsigned short* __restrict__ v2t, signed char* __restrict__ x1q,
    const float* __restrict__ sc) {
  __shared__ unsigned short Ks[128][72];    // k rows x d (padded)
  __shared__ unsigned short Vs[64][136];    // d x k-tile (padded)
  __shared__ unsigned short Ps[4][32][40];  // per-wave quantized P, 32-col chunk
  const int t = threadIdx.x;
  const int w = t >> 6, l = t & 63;
  const int lr = l & 15, lg = l >> 4;
  // XCD-bijective swizzle: 768 = 8 * 96
  const int bid = (int)(blockIdx.x & 7) * 96 + (int)(blockIdx.x >> 3);
  const int bh = bid >> 3, qc = bid & 7;
  const unsigned short* Qg = q2b + (size_t)bh * (SEQ * HD);
  const unsigned short* Kg = k2b + (size_t)bh * (SEQ * HD);
  const unsigned short* Vg = v2t + (size_t)bh * (SEQ * HD);
  const float aq = sc[2], ak = sc[4], av_ = sc[6], aa = sc[8], za = sc[9];
  const float ap = sc[10], zpp = sc[11];
  const float sqk2 = aq * ak * 0.125f * 1.44269504f;  // fold log2(e)
  const float spv = aa * av_;
  const int qr0 = qc * 128 + w * 32;

  bf16x8 qf[2][2];
#pragma unroll
  for (int rt = 0; rt < 2; ++rt)
#pragma unroll
    for (int ks = 0; ks < 2; ++ks)
      qf[rt][ks] = *(const bf16x8*)(Qg + (size_t)(qr0 + rt * 16 + lr) * HD + ks * 32 + lg * 8);

  const int sr = t >> 1, sc0 = (t & 1) * 32;
  const int vr = t >> 2, vc0 = (t & 3) * 32;

  // ---- pass 1: denominator only
  float lacc[2][4] = {};
  for (int kt = 0; kt < SEQ; kt += 128) {
    const uint4* g = (const uint4*)(Kg + (size_t)(kt + sr) * HD + sc0);
    uint4 u0 = g[0], u1 = g[1], u2 = g[2], u3 = g[3];
    __syncthreads();
    { uint4* d = (uint4*)&Ks[sr][sc0]; d[0] = u0; d[1] = u1; d[2] = u2; d[3] = u3; }
    __syncthreads();
#pragma unroll
    for (int ct = 0; ct < 8; ++ct) {
      const int kl = ct * 16 + lr;
      bf16x8 kf0 = *(const bf16x8*)&Ks[kl][lg * 8];
      bf16x8 kf1 = *(const bf16x8*)&Ks[kl][32 + lg * 8];
#pragma unroll
      for (int rt = 0; rt < 2; ++rt) {
        f32x4 s4 = {0.f, 0.f, 0.f, 0.f};
        s4 = MFMA_B16(qf[rt][0], kf0, s4);
        s4 = MFMA_B16(qf[rt][1], kf1, s4);
#pragma unroll
        for (int r = 0; r < 4; ++r)
          lacc[rt][r] += __builtin_amdgcn_exp2f(s4[r] * sqk2);
      }
    }
  }
#pragma unroll
  for (int off = 1; off < 16; off <<= 1)
#pragma unroll
    for (int rt = 0; rt < 2; ++rt)
#pragma unroll
      for (int r = 0; r < 4; ++r) lacc[rt][r] += __shfl_xor(lacc[rt][r], off);
  float pinv[2][4];
#pragma unroll
  for (int rt = 0; rt < 2; ++rt)
#pragma unroll
    for (int r = 0; r < 4; ++r) pinv[rt][r] = 1.0f / (lacc[rt][r] * aa);

  // ---- pass 2: recompute S, quantize P (32-col chunks) interleaved with PV
  f32x4 oacc[2][4] = {};
  for (int kt = 0; kt < SEQ; kt += 128) {
    const uint4* gk = (const uint4*)(Kg + (size_t)(kt + sr) * HD + sc0);
    uint4 u0 = gk[0], u1 = gk[1], u2 = gk[2], u3 = gk[3];
    const uint4* gv = (const uint4*)(Vg + (size_t)vr * SEQ + kt + vc0);
    uint4 w0 = gv[0], w1 = gv[1], w2 = gv[2], w3 = gv[3];
    __syncthreads();
    { uint4* d = (uint4*)&Ks[sr][sc0]; d[0] = u0; d[1] = u1; d[2] = u2; d[3] = u3; }
    { uint4* d = (uint4*)&Vs[vr][vc0]; d[0] = w0; d[1] = w1; d[2] = w2; d[3] = w3; }
    __syncthreads();
#pragma unroll
    for (int q4 = 0; q4 < 4; ++q4) {
#pragma unroll
      for (int c2 = 0; c2 < 2; ++c2) {
        const int ct = q4 * 2 + c2;
        const int kl = ct * 16 + lr;
        bf16x8 kf0 = *(const bf16x8*)&Ks[kl][lg * 8];
        bf16x8 kf1 = *(const bf16x8*)&Ks[kl][32 + lg * 8];
#pragma unroll
        for (int rt = 0; rt < 2; ++rt) {
          f32x4 s4 = {0.f, 0.f, 0.f, 0.f};
          s4 = MFMA_B16(qf[rt][0], kf0, s4);
          s4 = MFMA_B16(qf[rt][1], kf1, s4);
#pragma unroll
          for (int r = 0; r < 4; ++r) {
            float e = __builtin_amdgcn_exp2f(s4[r] * sqk2);
            float p = fmaf(e, pinv[rt][r], za);
            float qv = rintf(qclamp(p, 0.f, 15.f)) - za;
            Ps[w][rt * 16 + lg * 4 + r][c2 * 16 + lr] = f2bf(qv);
          }
        }
      }
      bf16x8 vf[4], pf[2];
#pragma unroll
      for (int dt = 0; dt < 4; ++dt)
        vf[dt] = *(const bf16x8*)&Vs[dt * 16 + lr][q4 * 32 + lg * 8];
#pragma unroll
      for (int rt = 0; rt < 2; ++rt)
        pf[rt] = *(const bf16x8*)&Ps[w][rt * 16 + lr][lg * 8];
#pragma unroll
      for (int rt = 0; rt < 2; ++rt)
#pragma unroll
        for (int dt = 0; dt < 4; ++dt)
          oacc[rt][dt] = MFMA_B16(pf[rt], vf[dt], oacc[rt][dt]);
    }
  }
  // ---- epilogue: x1 int part -> i8 (proj corrects zero-point via wsum)
  const int b_ = bh / HEADS, h_ = bh % HEADS;
#pragma unroll
  for (int rt = 0; rt < 2; ++rt)
#pragma unroll
    for (int dt = 0; dt < 4; ++dt) {
      const int col = h_ * HD + dt * 16 + lr;
#pragma unroll
      for (int r = 0; r < 4; ++r) {
        const int qrow = qr0 + rt * 16 + lg * 4 + r;
        float x1v = oacc[rt][dt][r] * spv;
        int xi = (int)rintf(qclamp(x1v / ap + zpp, -8.f, 7.f));
        x1q[(size_t)(b_ * SEQ + qrow) * DIM + col] = (signed char)xi;
      }
    }
}

extern "C" void kernel_launch(void* const* d_in, const int* in_sizes, int n_in,
                              void* d_out, int out_size, void* d_ws, size_t ws_size,
                              hipStream_t stream) {
  const float* x0      = (const float*)d_in[0];
  const float* qkvw    = (const float*)d_in[1];
  const float* qkv_aw  = (const float*)d_in[2];
  const float* qkv_aa  = (const float*)d_in[3];
  const float* qkv_azp = (const float*)d_in[4];
  const float* nqg     = (const float*)d_in[5];
  const float* nqb     = (const float*)d_in[6];
  const float* nkg     = (const float*)d_in[7];
  const float* nkb     = (const float*)d_in[8];
  const float* q_a     = (const float*)d_in[9];
  const float* q_z     = (const float*)d_in[10];
  const float* k_a     = (const float*)d_in[11];
  const float* k_z     = (const float*)d_in[12];
  const float* v_a     = (const float*)d_in[13];
  const float* v_z     = (const float*)d_in[14];
  const float* at_a    = (const float*)d_in[15];
  const float* at_z    = (const float*)d_in[16];
  const float* pw      = (const float*)d_in[17];
  const float* pb      = (const float*)d_in[18];
  const float* p_aw    = (const float*)d_in[19];
  const float* p_aa    = (const float*)d_in[20];
  const float* p_azp   = (const float*)d_in[21];
  float* out = (float*)d_out;

  char* ws = (char*)d_ws;
  size_t off = 0;
  float* scal = (float*)(ws); off = 256;
  signed char* x0q  = (signed char*)(ws + off); off += (size_t)NTOK * DIM;
  signed char* qwq  = (signed char*)(ws + off); off += (size_t)TRIPLE * DIM;
  signed char* pwq  = (signed char*)(ws + off); off += (size_t)DIM * DIM;
  float* wsumQ      = (float*)(ws + off);       off += (size_t)TRIPLE * 4;
  float* wsumP      = (float*)(ws + off);       off += (size_t)DIM * 4;
  unsigned short* q2b = (unsigned short*)(ws + off); off += (size_t)BHTOT * SEQ * HD * 2;
  unsigned short* k2b = (unsigned short*)(ws + off); off += (size_t)BHTOT * SEQ * HD * 2;
  unsigned short* v2t = (unsigned short*)(ws + off); off += (size_t)BHTOT * SEQ * HD * 2;
  signed char* x1q  = (signed char*)(ws + off); off += (size_t)NTOK * DIM;

  k_prep<<<1, 256, 0, stream>>>(qkv_aa, qkv_azp, q_a, q_z, k_a, k_z, v_a, v_z,
                                at_a, at_z, p_aa, p_azp, scal);
  k_quant_act<<<(NTOK * DIM) / 1024, 256, 0, stream>>>(x0, x0q, scal, NTOK * DIM);
  k_quant_w_ws<<<TRIPLE / 4, 256, 0, stream>>>(qkvw, qkv_aw, qwq, wsumQ);
  k_quant_w_ws<<<DIM / 4, 256, 0, stream>>>(pw, p_aw, pwq, wsumP);
  k_gemm_qkv<<<dim3(NTOK / 128, TRIPLE / 128), 256, 0, stream>>>(
      x0q, qwq, qkv_aw, wsumQ, scal, nqg, nqb, nkg, nkb, q2b, k2b, v2t);
  k_attn<<<BHTOT * 8, 256, 0, stream>>>(q2b, k2b, v2t, x1q, scal);
  k_gemm<<<dim3(NTOK / 64, DIM / 64), 256, 0, stream>>>(
      x1q, pwq, out, p_aw, wsumP, pb, scal, 10, 11, NTOK, DIM, DIM);
}